// Round 14
// baseline (348.000 us; speedup 1.0000x reference)
//
#include <hip/hip_runtime.h>
#include <hip/hip_bf16.h>
#include <math.h>
#include <stdint.h>

// B=8, P1=256 -> T=512 concat rows, C=1024, H=4096
#define TB_ 8
#define TT_ 512
#define TC_ 1024
// wkv chunked scan: 32 chunks of 16 steps
#define WKV_NCH 32
#define WKV_L 16

typedef __attribute__((ext_vector_type(8))) short bf16x8;
typedef __attribute__((ext_vector_type(4))) short s16x4;
typedef __attribute__((ext_vector_type(4))) float f32x4;

__device__ __forceinline__ float b2f(short u) {
  union { unsigned int i; float f; } x;
  x.i = ((unsigned int)(unsigned short)u) << 16;
  return x.f;
}
__device__ __forceinline__ short f2b(float f) {
  __hip_bfloat16 h = __float2bfloat16(f);  // RNE
  return __builtin_bit_cast(short, h);
}
__device__ __forceinline__ float sigm(float x) { return 1.0f / (1.0f + expf(-x)); }

// LIF over 4 identical inputs (closed form of the reference scan), TAU=2, VTH=1
__device__ __forceinline__ float lif4(float a) {
  float v = 0.0f, acc = 0.0f;
#pragma unroll
  for (int i = 0; i < 4; ++i) {
    v += (a - v) * 0.5f;
    float s = (v >= 1.0f) ? 1.0f : 0.0f;
    acc += s;
    v *= (1.0f - s);
  }
  return acc * 0.25f;
}

__device__ __forceinline__ void gload16(const void* g, void* l) {
  __builtin_amdgcn_global_load_lds(
      (__attribute__((address_space(1))) void*)(g),
      (__attribute__((address_space(3))) void*)(l), 16, 0, 0);
}

// counted vmcnt wait (compile-time immediate)
template <int N>
__device__ __forceinline__ void waitv() {
  if constexpr (N == 0)  asm volatile("s_waitcnt vmcnt(0)" ::: "memory");
  else if constexpr (N == 2)  asm volatile("s_waitcnt vmcnt(2)" ::: "memory");
  else if constexpr (N == 4)  asm volatile("s_waitcnt vmcnt(4)" ::: "memory");
  else if constexpr (N == 8)  asm volatile("s_waitcnt vmcnt(8)" ::: "memory");
  else if constexpr (N == 12) asm volatile("s_waitcnt vmcnt(12)" ::: "memory");
  else static_assert(N == 0, "unsupported vmcnt");
}
__device__ __forceinline__ void barrier_() {
  asm volatile("s_barrier" ::: "memory");
}

// ---------------- elementwise kernels ----------------

// fused concat + LayerNorm: row of xc = (t<256 ? x : rt); writes XC (f32 copy)
// and LN output (bf16). One 256-thread block per row (4096 rows).
__global__ __launch_bounds__(256) void ln_first(const float* __restrict__ x,
                                                const float* __restrict__ rt,
                                                float* __restrict__ xc,
                                                short* __restrict__ dst) {
  __shared__ float red[256];
  int row = blockIdx.x;  // b*512 + t
  int t = row & 511, b = row >> 9;
  const float* src = (t < 256) ? x + (int64_t)(b * 256 + t) * TC_
                               : rt + (int64_t)(t - 256) * TC_;
  float4 v = ((const float4*)src)[threadIdx.x];
  ((float4*)(xc + (int64_t)row * TC_))[threadIdx.x] = v;
  red[threadIdx.x] = v.x + v.y + v.z + v.w;
  __syncthreads();
  for (int off = 128; off > 0; off >>= 1) {
    if (threadIdx.x < off) red[threadIdx.x] += red[threadIdx.x + off];
    __syncthreads();
  }
  float mean = red[0] * (1.0f / 1024.0f);
  __syncthreads();
  float dx = v.x - mean, dy = v.y - mean, dz = v.z - mean, dw = v.w - mean;
  red[threadIdx.x] = dx * dx + dy * dy + dz * dz + dw * dw;
  __syncthreads();
  for (int off = 128; off > 0; off >>= 1) {
    if (threadIdx.x < off) red[threadIdx.x] += red[threadIdx.x + off];
    __syncthreads();
  }
  float rs = 1.0f / sqrtf(red[0] * (1.0f / 1024.0f) + 1e-6f);
  s16x4 o;
  o.x = f2b(dx * rs); o.y = f2b(dy * rs); o.z = f2b(dz * rs); o.w = f2b(dw * rs);
  *(s16x4*)(dst + (int64_t)row * TC_ + threadIdx.x * 4) = o;
}

// fused ln2 + channel-mix blend: per row r, compute LN(XC[r]) and LN(XC[r-1])
// (recompute; branch is block-uniform), blend with cmk/cmr, write bf16.
__global__ __launch_bounds__(256) void ln_mix2(const float* __restrict__ xc,
                                               const float* __restrict__ cmk,
                                               const float* __restrict__ cmr,
                                               short* __restrict__ xk,
                                               short* __restrict__ xr) {
  __shared__ float red[256];
  int row = blockIdx.x;
  int t = row & 511;
  int tid = threadIdx.x;
  float4 v = ((const float4*)(xc + (int64_t)row * TC_))[tid];
  red[tid] = v.x + v.y + v.z + v.w;
  __syncthreads();
  for (int off = 128; off > 0; off >>= 1) {
    if (tid < off) red[tid] += red[tid + off];
    __syncthreads();
  }
  float mean = red[0] * (1.0f / 1024.0f);
  __syncthreads();
  float dx = v.x - mean, dy = v.y - mean, dz = v.z - mean, dw = v.w - mean;
  red[tid] = dx * dx + dy * dy + dz * dz + dw * dw;
  __syncthreads();
  for (int off = 128; off > 0; off >>= 1) {
    if (tid < off) red[tid] += red[tid + off];
    __syncthreads();
  }
  float rs = 1.0f / sqrtf(red[0] * (1.0f / 1024.0f) + 1e-6f);
  float c0 = dx * rs, c1 = dy * rs, c2 = dz * rs, c3 = dw * rs;
  float p0 = 0.f, p1 = 0.f, p2 = 0.f, p3 = 0.f;
  if (t > 0) {  // block-uniform branch
    __syncthreads();
    float4 w4 = ((const float4*)(xc + (int64_t)(row - 1) * TC_))[tid];
    red[tid] = w4.x + w4.y + w4.z + w4.w;
    __syncthreads();
    for (int off = 128; off > 0; off >>= 1) {
      if (tid < off) red[tid] += red[tid + off];
      __syncthreads();
    }
    float meanp = red[0] * (1.0f / 1024.0f);
    __syncthreads();
    float ex = w4.x - meanp, ey = w4.y - meanp, ez = w4.z - meanp,
          ew = w4.w - meanp;
    red[tid] = ex * ex + ey * ey + ez * ez + ew * ew;
    __syncthreads();
    for (int off = 128; off > 0; off >>= 1) {
      if (tid < off) red[tid] += red[tid + off];
      __syncthreads();
    }
    float rsp = 1.0f / sqrtf(red[0] * (1.0f / 1024.0f) + 1e-6f);
    p0 = ex * rsp; p1 = ey * rsp; p2 = ez * rsp; p3 = ew * rsp;
  }
  int c = tid * 4;
  float k0 = cmk[c], k1 = cmk[c + 1], k2 = cmk[c + 2], k3 = cmk[c + 3];
  float r0 = cmr[c], r1 = cmr[c + 1], r2 = cmr[c + 2], r3 = cmr[c + 3];
  s16x4 ok, orr;
  ok.x = f2b(c0 * k0 + p0 * (1.0f - k0));
  ok.y = f2b(c1 * k1 + p1 * (1.0f - k1));
  ok.z = f2b(c2 * k2 + p2 * (1.0f - k2));
  ok.w = f2b(c3 * k3 + p3 * (1.0f - k3));
  orr.x = f2b(c0 * r0 + p0 * (1.0f - r0));
  orr.y = f2b(c1 * r1 + p1 * (1.0f - r1));
  orr.z = f2b(c2 * r2 + p2 * (1.0f - r2));
  orr.w = f2b(c3 * r3 + p3 * (1.0f - r3));
  *(s16x4*)(xk + (int64_t)row * TC_ + c) = ok;
  *(s16x4*)(xr + (int64_t)row * TC_ + c) = orr;
}

// time-mix blends from bf16 LN. 8 elems/thread; i over B*T*C/8.
__global__ __launch_bounds__(256) void mix3_b(const short* __restrict__ ln,
                                              const float* __restrict__ tk,
                                              const float* __restrict__ tv,
                                              const float* __restrict__ tr,
                                              short* __restrict__ xk,
                                              short* __restrict__ xv,
                                              short* __restrict__ xr) {
  int i = blockIdx.x * 256 + threadIdx.x;  // short8 index
  int c8 = i & 127;
  int t = (i >> 7) & 511;
  bf16x8 h = *(const bf16x8*)(ln + (int64_t)i * 8);
  bf16x8 s = {};
  if (t > 0) s = *(const bf16x8*)(ln + (int64_t)(i - 128) * 8);
  bf16x8 ok, ov, orr;
#pragma unroll
  for (int e = 0; e < 8; ++e) {
    float hf = b2f(h[e]), sf = b2f(s[e]);
    int c = c8 * 8 + e;
    float mk = tk[c], mv = tv[c], mr = tr[c];
    ok[e] = f2b(hf * mk + sf * (1.0f - mk));
    ov[e] = f2b(hf * mv + sf * (1.0f - mv));
    orr[e] = f2b(hf * mr + sf * (1.0f - mr));
  }
  *(bf16x8*)(xk + (int64_t)i * 8) = ok;
  *(bf16x8*)(xv + (int64_t)i * 8) = ov;
  *(bf16x8*)(xr + (int64_t)i * 8) = orr;
}

// f32 -> bf16, 8 elems/thread (used for Wck after its slot frees up)
__global__ __launch_bounds__(256) void cvt_b(const float* __restrict__ src,
                                             short* __restrict__ dst) {
  int64_t i = (int64_t)(blockIdx.x * 256 + threadIdx.x) * 8;
  float4 a = *(const float4*)(src + i);
  float4 b = *(const float4*)(src + i + 4);
  bf16x8 o;
  o[0] = f2b(a.x); o[1] = f2b(a.y); o[2] = f2b(a.z); o[3] = f2b(a.w);
  o[4] = f2b(b.x); o[5] = f2b(b.y); o[6] = f2b(b.z); o[7] = f2b(b.w);
  *(bf16x8*)(dst + i) = o;
}

// ONE launch: convert 8 weight arrays f32->bf16 + fused Wam row-sum.
__global__ __launch_bounds__(256) void cvt_all(
    const float* __restrict__ Wk, const float* __restrict__ Wv,
    const float* __restrict__ Wr, const float* __restrict__ Wo,
    const float* __restrict__ Wcr, const float* __restrict__ Wcv,
    const float* __restrict__ Wrm, const float* __restrict__ Wam,
    short* __restrict__ bWk, short* __restrict__ bWv, short* __restrict__ bWr,
    short* __restrict__ bWo, short* __restrict__ bWcr, short* __restrict__ bWcv,
    short* __restrict__ bWrm, short* __restrict__ bWam,
    float* __restrict__ S) {
  int bid = blockIdx.x;
  if (bid >= 4864) {  // Wam row-sums: 4 rows per block, 64 lanes per row
    int row = (bid - 4864) * 4 + (threadIdx.x >> 6);
    int lane = threadIdx.x & 63;
    float4 v = ((const float4*)(Wam + (int64_t)row * 256))[lane];
    float s = v.x + v.y + v.z + v.w;
    for (int off = 32; off > 0; off >>= 1) s += __shfl_down(s, off);
    if (lane == 0) S[row] = s;
    return;
  }
  const float* src; short* dst; int base;
  if (bid < 512)       { src = Wk;  dst = bWk;  base = bid; }
  else if (bid < 1024) { src = Wv;  dst = bWv;  base = bid - 512; }
  else if (bid < 1536) { src = Wr;  dst = bWr;  base = bid - 1024; }
  else if (bid < 2048) { src = Wo;  dst = bWo;  base = bid - 1536; }
  else if (bid < 2560) { src = Wcr; dst = bWcr; base = bid - 2048; }
  else if (bid < 4608) { src = Wcv; dst = bWcv; base = bid - 2560; }
  else if (bid < 4736) { src = Wrm; dst = bWrm; base = bid - 4608; }
  else                 { src = Wam; dst = bWam; base = bid - 4736; }
  int64_t i = ((int64_t)base * 256 + threadIdx.x) * 8;
  float4 a = *(const float4*)(src + i);
  float4 b = *(const float4*)(src + i + 4);
  bf16x8 o;
  o[0] = f2b(a.x); o[1] = f2b(a.y); o[2] = f2b(a.z); o[3] = f2b(a.w);
  o[4] = f2b(b.x); o[5] = f2b(b.y); o[6] = f2b(b.z); o[7] = f2b(b.w);
  *(bf16x8*)(dst + i) = o;
}

// ---------------- wkv chunked parallel scan ----------------
__global__ __launch_bounds__(256) void wkv_p1(const float* __restrict__ td,
                                              const short* __restrict__ K,
                                              const short* __restrict__ V,
                                              float* __restrict__ Ca,
                                              float* __restrict__ Da,
                                              float* __restrict__ Qa) {
  int bx = blockIdx.x;  // [ch:5][b:3][cg:2]
  int ch = bx >> 5;
  int b = (bx >> 2) & 7;
  int c = (bx & 3) * 256 + threadIdx.x;
  float w = -expf(td[c]);
  float aa = 0.0f, bb = 0.0f, pp = -1e38f;
  int64_t base = ((int64_t)b * TT_ + ch * WKV_L) * TC_ + c;
#pragma unroll
  for (int t = 0; t < WKV_L; ++t) {
    int64_t o = base + (int64_t)t * TC_;
    float kt = b2f(K[o]), vt = b2f(V[o]);
    float ww2 = pp + w;
    float p2 = fmaxf(ww2, kt);
    float e1 = expf(ww2 - p2);
    float e2 = expf(kt - p2);
    aa = e1 * aa + e2 * vt;
    bb = e1 * bb + e2;
    pp = p2;
  }
  int idx = ch * 8192 + b * 1024 + c;
  Ca[idx] = aa; Da[idx] = bb; Qa[idx] = pp;
}

__global__ __launch_bounds__(256) void wkv_p2(const float* __restrict__ td,
                                              const float* __restrict__ Ca,
                                              const float* __restrict__ Da,
                                              const float* __restrict__ Qa,
                                              float* __restrict__ Aa,
                                              float* __restrict__ Ba,
                                              float* __restrict__ Pa) {
  int i = blockIdx.x * 256 + threadIdx.x;  // 0..8191 = b*1024+c
  int c = i & (TC_ - 1);
  float wL = -expf(td[c]) * (float)WKV_L;
  float aa = 0.0f, bb = 0.0f, pp = -1e38f;
#pragma unroll 4
  for (int ch = 0; ch < WKV_NCH; ++ch) {
    int idx = ch * 8192 + i;
    Aa[idx] = aa; Ba[idx] = bb; Pa[idx] = pp;
    float ppw = pp + wL;
    float q = Qa[idx];
    float p2 = fmaxf(ppw, q);
    float ea = expf(ppw - p2);
    float eb = expf(q - p2);
    aa = aa * ea + Ca[idx] * eb;
    bb = bb * ea + Da[idx] * eb;
    pp = p2;
  }
}

__global__ __launch_bounds__(256) void wkv_p3(const float* __restrict__ td,
                                              const float* __restrict__ tf,
                                              const short* __restrict__ K,
                                              const short* __restrict__ V,
                                              const short* __restrict__ SR,
                                              short* __restrict__ SRY,
                                              const float* __restrict__ Aa,
                                              const float* __restrict__ Ba,
                                              const float* __restrict__ Pa) {
  int bx = blockIdx.x;
  int ch = bx >> 5;
  int b = (bx >> 2) & 7;
  int c = (bx & 3) * 256 + threadIdx.x;
  float w = -expf(td[c]);
  float u = tf[c];
  int idx = ch * 8192 + b * 1024 + c;
  float aa = Aa[idx], bb = Ba[idx], pp = Pa[idx];
  int64_t base = ((int64_t)b * TT_ + ch * WKV_L) * TC_ + c;
#pragma unroll
  for (int t = 0; t < WKV_L; ++t) {
    int64_t o = base + (int64_t)t * TC_;
    float kt = b2f(K[o]), vt = b2f(V[o]);
    float ww = u + kt;
    float p = fmaxf(pp, ww);
    float E1 = expf(pp - p);
    float E2 = expf(ww - p);
    float y = (E1 * aa + E2 * vt) / (E1 * bb + E2);
    SRY[o] = f2b(y * b2f(SR[o]));
    float ww2 = pp + w;
    float p2 = fmaxf(ww2, kt);
    float e1 = expf(ww2 - p2);
    float e2 = expf(kt - p2);
    aa = e1 * aa + e2 * vt;
    bb = e1 * bb + e2;
    pp = p2;
  }
}

// ---------------- LDS MFMA GEMM ----------------
// C[bz][m][n] = epi( sum_{k<K} A[m][k]*B[n][k] ), row stride Kst.
// BM x BN tile, BK=32, depth-D LDS ring in MFMA lane order (0 bank
// conflicts) + counted-vmcnt pipeline. GROUPS=2: 512 threads, waves 0-3
// (group 0) accumulate K/2 low half, waves 4-7 (group 1) the high half,
// each group on its own D-ring; wave w -> SIMD w&3 puts one wave of EACH
// group per SIMD -> ds_read of one overlaps MFMA of the other (the
// 1-wave/SIMD serialization at grid 256 was the measured bottleneck,
// MfmaUtil 15%). f32 partials reduced via LDS at the end (no bf16-partial
// numerics); group 0 applies the epilogue.
// EPI: 0 bf16; 1 sigmoid bf16; 2 relu^2 bf16;
//      3 tail-final f32 (e0=brm[m], e1=S[n], e2=bam[n], e3=XC f32, sE);
//      4 C(f32) += lif4(acc);
//      5 C(f32) += lif4(acc*e3[m][n]), rows t>=256 also write bf16 rtok (e1);
//      6 z-select: bz==2 ? sigmoid : plain (bf16)
template <int BM, int BN, int EPI, int D, int MINW, int GROUPS>
__global__ __launch_bounds__(256 * GROUPS, MINW) void gemm_bf16(
    const short* __restrict__ A, const short* __restrict__ B,
    void* __restrict__ Cp, int M, int N, int K, int Kst,
    int64_t sA, int64_t sB, int64_t sC,
    const float* __restrict__ e0, const float* __restrict__ e1,
    const float* __restrict__ e2, const void* __restrict__ e3, int64_t sE) {
  constexpr int MF = BM / 32;
  constexpr int NF = BN / 32;
  constexpr int ASLOT = BM / 64;
  constexpr int BSLOT = BN / 64;
  constexpr int NL = ASLOT + BSLOT;
  constexpr int SBUF = (BM + BN) * 32;
  __shared__ short lds[GROUPS * D * SBUF];
  const int tid = threadIdx.x;
  const int gtid = tid & 255;                      // within-group tid
  const int grp = (GROUPS > 1) ? (tid >> 8) : 0;   // k-split group
  short* glds = lds + grp * D * SBUF;

  // bijective XCD chunked swizzle (m204); requires nwg % 8 == 0
  const unsigned gx = gridDim.x, gy = gridDim.y;
  const unsigned nwg = gx * gy * gridDim.z;
  const unsigned lin = blockIdx.x + gx * (blockIdx.y + gy * blockIdx.z);
  const unsigned cs = nwg >> 3;
  const unsigned nl = (lin & 7) * cs + (lin >> 3);
  const unsigned bxs = nl % gx;
  const unsigned tmp = nl / gx;
  const unsigned bys = tmp % gy;
  const unsigned bz = tmp / gy;

  const int brow = bys * BM;
  const int bcol = bxs * BN;
  const int kbeg = grp * (K / GROUPS);
  const int ksteps = (K / GROUPS) / 32;
  const short* Ab = A + bz * sA + kbeg;
  const short* Bb = B + bz * sB + kbeg;

  const int srow = ((gtid >> 6) << 4) + (gtid & 15);
  const int skc = ((gtid >> 4) & 3) * 8;
  const short* gA[ASLOT];
  const short* gB[BSLOT];
#pragma unroll
  for (int s = 0; s < ASLOT; ++s)
    gA[s] = Ab + (int64_t)(brow + s * 64 + srow) * Kst + skc;
#pragma unroll
  for (int s = 0; s < BSLOT; ++s)
    gB[s] = Bb + (int64_t)(bcol + s * 64 + srow) * Kst + skc;

  const int lane = gtid & 63, wid = gtid >> 6;
  const int wr = wid >> 1, wc = wid & 1;

  f32x4 acc[MF][NF] = {};

  auto stage = [&](int buf, int k0) {
    short* d = glds + buf * SBUF;
#pragma unroll
    for (int s = 0; s < ASLOT; ++s)
      gload16(gA[s] + k0, d + s * 2048 + gtid * 8);
#pragma unroll
    for (int s = 0; s < BSLOT; ++s)
      gload16(gB[s] + k0, d + BM * 32 + s * 2048 + gtid * 8);
  };
  auto compute = [&](int buf) {
    const short* base = glds + buf * SBUF;
    bf16x8 af[MF], bfv[NF];
#pragma unroll
    for (int m = 0; m < MF; ++m)
      af[m] = *(const bf16x8*)(base + (wr * MF + m) * 512 + lane * 8);
#pragma unroll
    for (int n = 0; n < NF; ++n)
      bfv[n] = *(const bf16x8*)(base + BM * 32 + (wc * NF + n) * 512 + lane * 8);
#pragma unroll
    for (int m = 0; m < MF; ++m)
#pragma unroll
      for (int n = 0; n < NF; ++n)
        acc[m][n] = __builtin_amdgcn_mfma_f32_16x16x32_bf16(af[m], bfv[n],
                                                            acc[m][n], 0, 0, 0);
  };

#pragma unroll
  for (int d = 0; d < D - 1; ++d) stage(d, d * 32);
  for (int t = 0; t <= ksteps - D; ++t) {
    stage((t + D - 1) & (D - 1), (t + D - 1) * 32);
    waitv<(D - 1) * NL>();
    barrier_();
    compute(t & (D - 1));
    barrier_();
  }
  {
    int t = ksteps - D + 1;
    if constexpr (D >= 4) {
      waitv<2 * NL>(); barrier_(); compute(t & (D - 1)); barrier_(); ++t;
      waitv<1 * NL>(); barrier_(); compute(t & (D - 1)); barrier_(); ++t;
    }
    waitv<0>(); barrier_(); compute(t & (D - 1));
  }

  // k-split reduction: group 1 -> LDS (conflict-free i*256+gtid layout),
  // group 0 adds and runs the epilogue.
  if constexpr (GROUPS == 2) {
    __syncthreads();
    float* red = (float*)lds;
    if (grp == 1) {
#pragma unroll
      for (int m = 0; m < MF; ++m)
#pragma unroll
        for (int n = 0; n < NF; ++n)
#pragma unroll
          for (int j = 0; j < 4; ++j)
            red[(((m * NF) + n) * 4 + j) * 256 + gtid] = acc[m][n][j];
    }
    __syncthreads();
    if (grp != 0) return;
#pragma unroll
    for (int m = 0; m < MF; ++m)
#pragma unroll
      for (int n = 0; n < NF; ++n)
#pragma unroll
        for (int j = 0; j < 4; ++j)
          acc[m][n][j] += red[(((m * NF) + n) * 4 + j) * 256 + gtid];
  }

  const int r0 = brow + wr * (BM / 2) + (lane >> 4) * 4;
  const int c0 = bcol + wc * (BN / 2) + (lane & 15);
#pragma unroll
  for (int m = 0; m < MF; ++m) {
#pragma unroll
    for (int j = 0; j < 4; ++j) {
      int row = r0 + m * 16 + j;
#pragma unroll
      for (int n = 0; n < NF; ++n) {
        int col = c0 + n * 16;
        float v = acc[m][n][j];
        int64_t idx = (int64_t)row * N + col;
        if (EPI == 0) {
          ((short*)Cp)[bz * sC + idx] = f2b(v);
        } else if (EPI == 1) {
          ((short*)Cp)[bz * sC + idx] = f2b(sigm(v));
        } else if (EPI == 2) {
          v = fmaxf(v, 0.0f);
          ((short*)Cp)[bz * sC + idx] = f2b(v * v);
        } else if (EPI == 3) {
          float r2 = v + e0[row] * e1[col] + e2[col];
          float xo = ((const float*)e3)[bz * sE + idx];
          ((float*)Cp)[bz * sC + idx] = xo * (1.0f + r2);
        } else if (EPI == 4) {
          float* XC = (float*)Cp;
          XC[idx] = XC[idx] + lif4(v);
        } else if (EPI == 5) {
          float* XC = (float*)Cp;
          float srr = b2f(((const short*)e3)[idx]);
          float nv = XC[idx] + lif4(v * srr);
          XC[idx] = nv;
          int tt = row & 511;
          if (tt >= 256) {  // fused rtok emit (b, t-256, col) bf16
            short* rtok = (short*)(void*)const_cast<float*>(e1);
            rtok[(((int64_t)(row >> 9)) * 256 + (tt - 256)) * 1024 + col] =
                f2b(nv);
          }
        } else if (EPI == 6) {
          ((short*)Cp)[bz * sC + idx] = f2b(bz == 2 ? sigm(v) : v);
        }
      }
    }
  }
}

// ---------------- launch ----------------
extern "C" void kernel_launch(void* const* d_in, const int* in_sizes, int n_in,
                              void* d_out, int out_size, void* d_ws,
                              size_t ws_size, hipStream_t stream) {
  const float* x   = (const float*)d_in[0];
  const float* rt  = (const float*)d_in[1];
  const float* td  = (const float*)d_in[2];
  const float* tf  = (const float*)d_in[3];
  const float* tmk = (const float*)d_in[4];
  const float* tmv = (const float*)d_in[5];
  const float* tmr = (const float*)d_in[6];
  const float* Wk  = (const float*)d_in[7];
  const float* Wv  = (const float*)d_in[8];
  const float* Wr  = (const float*)d_in[9];
  const float* Wo  = (const float*)d_in[10];
  const float* cmk = (const float*)d_in[11];
  const float* cmr = (const float*)d_in[12];
  const float* Wck = (const float*)d_in[13];
  const float* Wcv = (const float*)d_in[14];
  const float* Wcr = (const float*)d_in[15];
  const float* Wrm = (const float*)d_in[16];
  const float* brm = (const float*)d_in[17];
  const float* Wam = (const float*)d_in[18];
  const float* bam = (const float*)d_in[19];
  float* out = (float*)d_out;

  const size_t MB = 1ull << 20;
  uint8_t* W8 = (uint8_t*)d_ws;
  // Memory map (MB offsets), phase-ordered reuse (R8-proven layout):
  float* XC   = (float*)(W8);                        // 0-16 residual f32
  short* L    = (short*)(W8 + 16 * MB);              // 16-24 ln1 out
  short* S1   = (short*)(W8 + 24 * MB);              // 24-32 xk / SRY / SRR
  short* S2   = (short*)(W8 + 32 * MB);              // 32-40 xv / xk2 / rtok,Mt
  short* S3   = (short*)(W8 + 40 * MB);              // 40-48 xr / xr2 / bWck
  short* bWcv = (short*)(W8 + 48 * MB);              // 48-56
  short* bWk  = (short*)(W8 + 56 * MB);              // 56-62 bWk,bWv,bWr contig
  short* bWo  = (short*)(W8 + 62 * MB);
  short* bWcr = (short*)(W8 + 64 * MB);
  short* bWrm = (short*)(W8 + 66 * MB);              // 0.5 MB
  short* bWam = (short*)(W8 + 66 * MB + 512 * 1024); // 0.5 MB
  short* KK   = (short*)(W8 + 67 * MB);              // 67-75
  short* VV   = (short*)(W8 + 75 * MB);              // 75-83
  short* RR   = (short*)(W8 + 83 * MB);              // 83-91
  float* Ca   = (float*)(W8 + 91 * MB);              // wkv temps 91-97
  float* Da   = (float*)(W8 + 92 * MB);
  float* Qa   = (float*)(W8 + 93 * MB);
  float* Aa   = (float*)(W8 + 94 * MB);
  float* Ba   = (float*)(W8 + 95 * MB);
  float* Pa   = (float*)(W8 + 96 * MB);
  short* SRY  = S1;
  short* xk2  = S2;
  short* xr2  = S3;
  short* SRR  = S1;                                  // written step 6
  short* bWck = S3;                                  // after SRR GEMM
  short* H16  = KK;                                  // 67-99 (32 MB)
  short* rtok = S2;                                  // 32-36 (tail)
  short* Mt   = (short*)(W8 + 36 * MB);              // 36-37 (tail)
  float* Sb   = (float*)(W8 + 99 * MB);              // 4 KB, aliases nothing

  dim3 blk(256);
  dim3 blk2(512);
  const int NV8 = 2048;

  // 0) ALL weight conversions + Wam row-sum in one launch
  cvt_all<<<5120, blk, 0, stream>>>(Wk, Wv, Wr, Wo, Wcr, Wcv, Wrm, Wam,
                                    bWk, bWk + 1048576, bWk + 2097152, bWo,
                                    bWcr, bWcv, bWrm, bWam, Sb);

  // 1) fused concat+ln1 -> XC, L; mixes -> S1,S2,S3
  ln_first<<<TB_ * TT_, blk, 0, stream>>>(x, rt, XC, L);
  mix3_b<<<NV8, blk, 0, stream>>>(L, tmk, tmv, tmr, S1, S2, S3);

  // 2) fused z=3 time-mix: KK = xk*Wk^T, VV = xv*Wv^T, RR = sigm(xr*Wr^T)
  //    (grid 768 = 3 blk/CU, 256-thr, D=2, GROUPS=1)
  gemm_bf16<128, 128, 6, 2, 3, 1><<<dim3(8, 32, 3), blk, 0, stream>>>(
      S1, bWk, KK, 4096, 1024, 1024, 1024, 4194304, 1048576, 4194304,
      nullptr, nullptr, nullptr, nullptr, 0);
  // 3) wkv chunked scan -> SRY (=S1)
  wkv_p1<<<WKV_NCH * TB_ * 4, blk, 0, stream>>>(td, KK, VV, Ca, Da, Qa);
  wkv_p2<<<32, blk, 0, stream>>>(td, Ca, Da, Qa, Aa, Ba, Pa);
  wkv_p3<<<WKV_NCH * TB_ * 4, blk, 0, stream>>>(td, tf, KK, VV, RR, SRY,
                                                Aa, Ba, Pa);
  // 4) att: XC += lif(SRY*Wo^T)   (grid 256, 512-thr k-split: 2 waves/SIMD)
  gemm_bf16<128, 128, 4, 2, 1, 2><<<dim3(8, 32, 1), blk2, 0, stream>>>(
      SRY, bWo, XC, 4096, 1024, 1024, 1024, 0, 0, 0,
      nullptr, nullptr, nullptr, nullptr, 0);
  // 5) fused ln2+mix2 -> xk2(S2), xr2(S3)
  ln_mix2<<<TB_ * TT_, blk, 0, stream>>>(XC, cmk, cmr, xk2, xr2);
  // 6) SRR = sigm(xr2*Wcr^T) -> S1  (k-split)
  gemm_bf16<128, 128, 1, 2, 1, 2><<<dim3(8, 32, 1), blk2, 0, stream>>>(
      xr2, bWcr, SRR, 4096, 1024, 1024, 1024, 0, 0, 0,
      nullptr, nullptr, nullptr, nullptr, 0);
  // 7) Wck -> bf16 into now-dead xr2 slot
  cvt_b<<<2048, blk, 0, stream>>>(Wck, bWck);
  // 8) H = relu^2(xk2*Wck^T) -> H16  (grid 1024, 512-thr k-split, 2 blk/CU)
  gemm_bf16<128, 128, 2, 2, 1, 2><<<dim3(32, 32, 1), blk2, 0, stream>>>(
      xk2, bWck, H16, 4096, 4096, 1024, 1024, 0, 0, 0,
      nullptr, nullptr, nullptr, nullptr, 0);
  // 9) XC += lif(SRR*(H*Wcv^T)); rows t>=256 also emit rtok bf16 (k-split)
  gemm_bf16<128, 128, 5, 2, 1, 2><<<dim3(8, 32, 1), blk2, 0, stream>>>(
      H16, bWcv, XC, 4096, 1024, 4096, 4096, 0, 0, 0,
      nullptr, (const float*)rtok, nullptr, SRR, 0);
  // 10) tail: Mt = Wrm x rtok^T per batch; out = xo*(1+Mt*Wam^T+brm*S+bam)
  gemm_bf16<64, 64, 0, 2, 2, 1><<<dim3(4, 4, 8), blk, 0, stream>>>(
      bWrm, rtok, Mt, 256, 256, 1024, 1024, 0, (int64_t)256 * 1024,
      (int64_t)256 * 256, nullptr, nullptr, nullptr, nullptr, 0);
  gemm_bf16<64, 64, 3, 2, 2, 1><<<dim3(16, 4, 8), blk, 0, stream>>>(
      Mt, bWam, out, 256, 1024, 256, 256, (int64_t)256 * 256, 0,
      (int64_t)256 * 1024, brm, Sb, bam, XC, (int64_t)512 * 1024);
}

// Round 15
// 342.752 us; speedup vs baseline: 1.0153x; 1.0153x over previous
//
#include <hip/hip_runtime.h>
#include <hip/hip_bf16.h>
#include <math.h>
#include <stdint.h>

// B=8, P1=256 -> T=512 concat rows, C=1024, H=4096
#define TB_ 8
#define TT_ 512
#define TC_ 1024
// wkv chunked scan: 32 chunks of 16 steps
#define WKV_NCH 32
#define WKV_L 16

typedef __attribute__((ext_vector_type(8))) short bf16x8;
typedef __attribute__((ext_vector_type(4))) short s16x4;
typedef __attribute__((ext_vector_type(4))) float f32x4;

__device__ __forceinline__ float b2f(short u) {
  union { unsigned int i; float f; } x;
  x.i = ((unsigned int)(unsigned short)u) << 16;
  return x.f;
}
__device__ __forceinline__ short f2b(float f) {
  __hip_bfloat16 h = __float2bfloat16(f);  // RNE
  return __builtin_bit_cast(short, h);
}
__device__ __forceinline__ float sigm(float x) { return 1.0f / (1.0f + expf(-x)); }

// LIF over 4 identical inputs (closed form of the reference scan), TAU=2, VTH=1
__device__ __forceinline__ float lif4(float a) {
  float v = 0.0f, acc = 0.0f;
#pragma unroll
  for (int i = 0; i < 4; ++i) {
    v += (a - v) * 0.5f;
    float s = (v >= 1.0f) ? 1.0f : 0.0f;
    acc += s;
    v *= (1.0f - s);
  }
  return acc * 0.25f;
}

__device__ __forceinline__ void gload16(const void* g, void* l) {
  __builtin_amdgcn_global_load_lds(
      (__attribute__((address_space(1))) void*)(g),
      (__attribute__((address_space(3))) void*)(l), 16, 0, 0);
}

// counted vmcnt wait (compile-time immediate)
template <int N>
__device__ __forceinline__ void waitv() {
  if constexpr (N == 0)  asm volatile("s_waitcnt vmcnt(0)" ::: "memory");
  else if constexpr (N == 2)  asm volatile("s_waitcnt vmcnt(2)" ::: "memory");
  else if constexpr (N == 4)  asm volatile("s_waitcnt vmcnt(4)" ::: "memory");
  else if constexpr (N == 8)  asm volatile("s_waitcnt vmcnt(8)" ::: "memory");
  else if constexpr (N == 12) asm volatile("s_waitcnt vmcnt(12)" ::: "memory");
  else if constexpr (N == 16) asm volatile("s_waitcnt vmcnt(16)" ::: "memory");
  else if constexpr (N == 20) asm volatile("s_waitcnt vmcnt(20)" ::: "memory");
  else if constexpr (N == 24) asm volatile("s_waitcnt vmcnt(24)" ::: "memory");
  else if constexpr (N == 28) asm volatile("s_waitcnt vmcnt(28)" ::: "memory");
  else static_assert(N == 0, "unsupported vmcnt");
}
__device__ __forceinline__ void barrier_() {
  asm volatile("s_barrier" ::: "memory");
}

// ---------------- elementwise kernels ----------------

// FUSED concat + ln1 + time-mix blends. One 256-thread block per row.
// Computes LN(xc[row]) and LN(xc[row-1]) (recompute, block-uniform branch),
// writes XC (f32) and the three blended bf16 operands xk/xv/xr.
__global__ __launch_bounds__(256) void ln_mix3(
    const float* __restrict__ x, const float* __restrict__ rt,
    const float* __restrict__ tmk, const float* __restrict__ tmv,
    const float* __restrict__ tmr, float* __restrict__ xc,
    short* __restrict__ xk, short* __restrict__ xv, short* __restrict__ xr) {
  __shared__ float red[256];
  int row = blockIdx.x;  // b*512 + t
  int t = row & 511, b = row >> 9;
  int tid = threadIdx.x;
  const float* src = (t < 256) ? x + (int64_t)(b * 256 + t) * TC_
                               : rt + (int64_t)(t - 256) * TC_;
  float4 v = ((const float4*)src)[tid];
  ((float4*)(xc + (int64_t)row * TC_))[tid] = v;
  red[tid] = v.x + v.y + v.z + v.w;
  __syncthreads();
  for (int off = 128; off > 0; off >>= 1) {
    if (tid < off) red[tid] += red[tid + off];
    __syncthreads();
  }
  float mean = red[0] * (1.0f / 1024.0f);
  __syncthreads();
  float dx = v.x - mean, dy = v.y - mean, dz = v.z - mean, dw = v.w - mean;
  red[tid] = dx * dx + dy * dy + dz * dz + dw * dw;
  __syncthreads();
  for (int off = 128; off > 0; off >>= 1) {
    if (tid < off) red[tid] += red[tid + off];
    __syncthreads();
  }
  float rs = 1.0f / sqrtf(red[0] * (1.0f / 1024.0f) + 1e-6f);
  float c0 = dx * rs, c1 = dy * rs, c2 = dz * rs, c3 = dw * rs;
  float p0 = 0.f, p1 = 0.f, p2 = 0.f, p3 = 0.f;
  if (t > 0) {  // block-uniform
    int tp = t - 1;
    const float* srcp = (tp < 256) ? x + (int64_t)(b * 256 + tp) * TC_
                                   : rt + (int64_t)(tp - 256) * TC_;
    __syncthreads();
    float4 w4 = ((const float4*)srcp)[tid];
    red[tid] = w4.x + w4.y + w4.z + w4.w;
    __syncthreads();
    for (int off = 128; off > 0; off >>= 1) {
      if (tid < off) red[tid] += red[tid + off];
      __syncthreads();
    }
    float meanp = red[0] * (1.0f / 1024.0f);
    __syncthreads();
    float ex = w4.x - meanp, ey = w4.y - meanp, ez = w4.z - meanp,
          ew = w4.w - meanp;
    red[tid] = ex * ex + ey * ey + ez * ez + ew * ew;
    __syncthreads();
    for (int off = 128; off > 0; off >>= 1) {
      if (tid < off) red[tid] += red[tid + off];
      __syncthreads();
    }
    float rsp = 1.0f / sqrtf(red[0] * (1.0f / 1024.0f) + 1e-6f);
    p0 = ex * rsp; p1 = ey * rsp; p2 = ez * rsp; p3 = ew * rsp;
  }
  int c = tid * 4;
  int64_t o = (int64_t)row * TC_ + c;
  float m0, m1, m2, m3;
  s16x4 ov;
  m0 = tmk[c]; m1 = tmk[c + 1]; m2 = tmk[c + 2]; m3 = tmk[c + 3];
  ov.x = f2b(c0 * m0 + p0 * (1.0f - m0));
  ov.y = f2b(c1 * m1 + p1 * (1.0f - m1));
  ov.z = f2b(c2 * m2 + p2 * (1.0f - m2));
  ov.w = f2b(c3 * m3 + p3 * (1.0f - m3));
  *(s16x4*)(xk + o) = ov;
  m0 = tmv[c]; m1 = tmv[c + 1]; m2 = tmv[c + 2]; m3 = tmv[c + 3];
  ov.x = f2b(c0 * m0 + p0 * (1.0f - m0));
  ov.y = f2b(c1 * m1 + p1 * (1.0f - m1));
  ov.z = f2b(c2 * m2 + p2 * (1.0f - m2));
  ov.w = f2b(c3 * m3 + p3 * (1.0f - m3));
  *(s16x4*)(xv + o) = ov;
  m0 = tmr[c]; m1 = tmr[c + 1]; m2 = tmr[c + 2]; m3 = tmr[c + 3];
  ov.x = f2b(c0 * m0 + p0 * (1.0f - m0));
  ov.y = f2b(c1 * m1 + p1 * (1.0f - m1));
  ov.z = f2b(c2 * m2 + p2 * (1.0f - m2));
  ov.w = f2b(c3 * m3 + p3 * (1.0f - m3));
  *(s16x4*)(xr + o) = ov;
}

// fused ln2 + channel-mix blend (same recompute pattern).
__global__ __launch_bounds__(256) void ln_mix2(const float* __restrict__ xc,
                                               const float* __restrict__ cmk,
                                               const float* __restrict__ cmr,
                                               short* __restrict__ xk,
                                               short* __restrict__ xr) {
  __shared__ float red[256];
  int row = blockIdx.x;
  int t = row & 511;
  int tid = threadIdx.x;
  float4 v = ((const float4*)(xc + (int64_t)row * TC_))[tid];
  red[tid] = v.x + v.y + v.z + v.w;
  __syncthreads();
  for (int off = 128; off > 0; off >>= 1) {
    if (tid < off) red[tid] += red[tid + off];
    __syncthreads();
  }
  float mean = red[0] * (1.0f / 1024.0f);
  __syncthreads();
  float dx = v.x - mean, dy = v.y - mean, dz = v.z - mean, dw = v.w - mean;
  red[tid] = dx * dx + dy * dy + dz * dz + dw * dw;
  __syncthreads();
  for (int off = 128; off > 0; off >>= 1) {
    if (tid < off) red[tid] += red[tid + off];
    __syncthreads();
  }
  float rs = 1.0f / sqrtf(red[0] * (1.0f / 1024.0f) + 1e-6f);
  float c0 = dx * rs, c1 = dy * rs, c2 = dz * rs, c3 = dw * rs;
  float p0 = 0.f, p1 = 0.f, p2 = 0.f, p3 = 0.f;
  if (t > 0) {  // block-uniform branch
    __syncthreads();
    float4 w4 = ((const float4*)(xc + (int64_t)(row - 1) * TC_))[tid];
    red[tid] = w4.x + w4.y + w4.z + w4.w;
    __syncthreads();
    for (int off = 128; off > 0; off >>= 1) {
      if (tid < off) red[tid] += red[tid + off];
      __syncthreads();
    }
    float meanp = red[0] * (1.0f / 1024.0f);
    __syncthreads();
    float ex = w4.x - meanp, ey = w4.y - meanp, ez = w4.z - meanp,
          ew = w4.w - meanp;
    red[tid] = ex * ex + ey * ey + ez * ez + ew * ew;
    __syncthreads();
    for (int off = 128; off > 0; off >>= 1) {
      if (tid < off) red[tid] += red[tid + off];
      __syncthreads();
    }
    float rsp = 1.0f / sqrtf(red[0] * (1.0f / 1024.0f) + 1e-6f);
    p0 = ex * rsp; p1 = ey * rsp; p2 = ez * rsp; p3 = ew * rsp;
  }
  int c = tid * 4;
  float k0 = cmk[c], k1 = cmk[c + 1], k2 = cmk[c + 2], k3 = cmk[c + 3];
  float r0 = cmr[c], r1 = cmr[c + 1], r2 = cmr[c + 2], r3 = cmr[c + 3];
  s16x4 ok, orr;
  ok.x = f2b(c0 * k0 + p0 * (1.0f - k0));
  ok.y = f2b(c1 * k1 + p1 * (1.0f - k1));
  ok.z = f2b(c2 * k2 + p2 * (1.0f - k2));
  ok.w = f2b(c3 * k3 + p3 * (1.0f - k3));
  orr.x = f2b(c0 * r0 + p0 * (1.0f - r0));
  orr.y = f2b(c1 * r1 + p1 * (1.0f - r1));
  orr.z = f2b(c2 * r2 + p2 * (1.0f - r2));
  orr.w = f2b(c3 * r3 + p3 * (1.0f - r3));
  *(s16x4*)(xk + (int64_t)row * TC_ + c) = ok;
  *(s16x4*)(xr + (int64_t)row * TC_ + c) = orr;
}

// f32 -> bf16, 8 elems/thread (used for Wck after its slot frees up)
__global__ __launch_bounds__(256) void cvt_b(const float* __restrict__ src,
                                             short* __restrict__ dst) {
  int64_t i = (int64_t)(blockIdx.x * 256 + threadIdx.x) * 8;
  float4 a = *(const float4*)(src + i);
  float4 b = *(const float4*)(src + i + 4);
  bf16x8 o;
  o[0] = f2b(a.x); o[1] = f2b(a.y); o[2] = f2b(a.z); o[3] = f2b(a.w);
  o[4] = f2b(b.x); o[5] = f2b(b.y); o[6] = f2b(b.z); o[7] = f2b(b.w);
  *(bf16x8*)(dst + i) = o;
}

// ONE launch: convert 8 weight arrays f32->bf16 + fused Wam row-sum.
__global__ __launch_bounds__(256) void cvt_all(
    const float* __restrict__ Wk, const float* __restrict__ Wv,
    const float* __restrict__ Wr, const float* __restrict__ Wo,
    const float* __restrict__ Wcr, const float* __restrict__ Wcv,
    const float* __restrict__ Wrm, const float* __restrict__ Wam,
    short* __restrict__ bWk, short* __restrict__ bWv, short* __restrict__ bWr,
    short* __restrict__ bWo, short* __restrict__ bWcr, short* __restrict__ bWcv,
    short* __restrict__ bWrm, short* __restrict__ bWam,
    float* __restrict__ S) {
  int bid = blockIdx.x;
  if (bid >= 4864) {  // Wam row-sums: 4 rows per block, 64 lanes per row
    int row = (bid - 4864) * 4 + (threadIdx.x >> 6);
    int lane = threadIdx.x & 63;
    float4 v = ((const float4*)(Wam + (int64_t)row * 256))[lane];
    float s = v.x + v.y + v.z + v.w;
    for (int off = 32; off > 0; off >>= 1) s += __shfl_down(s, off);
    if (lane == 0) S[row] = s;
    return;
  }
  const float* src; short* dst; int base;
  if (bid < 512)       { src = Wk;  dst = bWk;  base = bid; }
  else if (bid < 1024) { src = Wv;  dst = bWv;  base = bid - 512; }
  else if (bid < 1536) { src = Wr;  dst = bWr;  base = bid - 1024; }
  else if (bid < 2048) { src = Wo;  dst = bWo;  base = bid - 1536; }
  else if (bid < 2560) { src = Wcr; dst = bWcr; base = bid - 2048; }
  else if (bid < 4608) { src = Wcv; dst = bWcv; base = bid - 2560; }
  else if (bid < 4736) { src = Wrm; dst = bWrm; base = bid - 4608; }
  else                 { src = Wam; dst = bWam; base = bid - 4736; }
  int64_t i = ((int64_t)base * 256 + threadIdx.x) * 8;
  float4 a = *(const float4*)(src + i);
  float4 b = *(const float4*)(src + i + 4);
  bf16x8 o;
  o[0] = f2b(a.x); o[1] = f2b(a.y); o[2] = f2b(a.z); o[3] = f2b(a.w);
  o[4] = f2b(b.x); o[5] = f2b(b.y); o[6] = f2b(b.z); o[7] = f2b(b.w);
  *(bf16x8*)(dst + i) = o;
}

// ---------------- wkv chunked parallel scan ----------------
__global__ __launch_bounds__(256) void wkv_p1(const float* __restrict__ td,
                                              const short* __restrict__ K,
                                              const short* __restrict__ V,
                                              float* __restrict__ Ca,
                                              float* __restrict__ Da,
                                              float* __restrict__ Qa) {
  int bx = blockIdx.x;  // [ch:5][b:3][cg:2]
  int ch = bx >> 5;
  int b = (bx >> 2) & 7;
  int c = (bx & 3) * 256 + threadIdx.x;
  float w = -expf(td[c]);
  float aa = 0.0f, bb = 0.0f, pp = -1e38f;
  int64_t base = ((int64_t)b * TT_ + ch * WKV_L) * TC_ + c;
#pragma unroll
  for (int t = 0; t < WKV_L; ++t) {
    int64_t o = base + (int64_t)t * TC_;
    float kt = b2f(K[o]), vt = b2f(V[o]);
    float ww2 = pp + w;
    float p2 = fmaxf(ww2, kt);
    float e1 = expf(ww2 - p2);
    float e2 = expf(kt - p2);
    aa = e1 * aa + e2 * vt;
    bb = e1 * bb + e2;
    pp = p2;
  }
  int idx = ch * 8192 + b * 1024 + c;
  Ca[idx] = aa; Da[idx] = bb; Qa[idx] = pp;
}

__global__ __launch_bounds__(256) void wkv_p2(const float* __restrict__ td,
                                              const float* __restrict__ Ca,
                                              const float* __restrict__ Da,
                                              const float* __restrict__ Qa,
                                              float* __restrict__ Aa,
                                              float* __restrict__ Ba,
                                              float* __restrict__ Pa) {
  int i = blockIdx.x * 256 + threadIdx.x;  // 0..8191 = b*1024+c
  int c = i & (TC_ - 1);
  float wL = -expf(td[c]) * (float)WKV_L;
  float aa = 0.0f, bb = 0.0f, pp = -1e38f;
#pragma unroll 4
  for (int ch = 0; ch < WKV_NCH; ++ch) {
    int idx = ch * 8192 + i;
    Aa[idx] = aa; Ba[idx] = bb; Pa[idx] = pp;
    float ppw = pp + wL;
    float q = Qa[idx];
    float p2 = fmaxf(ppw, q);
    float ea = expf(ppw - p2);
    float eb = expf(q - p2);
    aa = aa * ea + Ca[idx] * eb;
    bb = bb * ea + Da[idx] * eb;
    pp = p2;
  }
}

__global__ __launch_bounds__(256) void wkv_p3(const float* __restrict__ td,
                                              const float* __restrict__ tf,
                                              const short* __restrict__ K,
                                              const short* __restrict__ V,
                                              const short* __restrict__ SR,
                                              short* __restrict__ SRY,
                                              const float* __restrict__ Aa,
                                              const float* __restrict__ Ba,
                                              const float* __restrict__ Pa) {
  int bx = blockIdx.x;
  int ch = bx >> 5;
  int b = (bx >> 2) & 7;
  int c = (bx & 3) * 256 + threadIdx.x;
  float w = -expf(td[c]);
  float u = tf[c];
  int idx = ch * 8192 + b * 1024 + c;
  float aa = Aa[idx], bb = Ba[idx], pp = Pa[idx];
  int64_t base = ((int64_t)b * TT_ + ch * WKV_L) * TC_ + c;
#pragma unroll
  for (int t = 0; t < WKV_L; ++t) {
    int64_t o = base + (int64_t)t * TC_;
    float kt = b2f(K[o]), vt = b2f(V[o]);
    float ww = u + kt;
    float p = fmaxf(pp, ww);
    float E1 = expf(pp - p);
    float E2 = expf(ww - p);
    float y = (E1 * aa + E2 * vt) / (E1 * bb + E2);
    SRY[o] = f2b(y * b2f(SR[o]));
    float ww2 = pp + w;
    float p2 = fmaxf(ww2, kt);
    float e1 = expf(ww2 - p2);
    float e2 = expf(kt - p2);
    aa = e1 * aa + e2 * vt;
    bb = e1 * bb + e2;
    pp = p2;
  }
}

// ---------------- LDS MFMA GEMM ----------------
// C[bz][m][n] = epi( sum_{k<K} A[m][k]*B[n][k] ), row stride Kst.
// BM x BN tile, BK=32, 256 threads (4 waves 2x2), depth-D LDS ring in MFMA
// lane order (0 bank conflicts) + counted-vmcnt pipeline. Measured best:
// 1 blk/CU (grid 256) -> D=8; >=3 blk/CU -> D=2 (m114 inter-block overlap).
// EPI: 0 bf16; 1 sigmoid bf16; 2 relu^2 bf16;
//      3 tail-final f32 (e0=brm[m], e1=S[n], e2=bam[n], e3=XC f32, sE);
//      4 C(f32) += lif4(acc);
//      5 C(f32) += lif4(acc*e3[m][n]), rows t>=256 also write bf16 rtok (e1);
//      6 z-select: bz==2 ? sigmoid : plain (bf16)
template <int BM, int BN, int EPI, int D, int MINW>
__global__ __launch_bounds__(256, MINW) void gemm_bf16(
    const short* __restrict__ A, const short* __restrict__ B,
    void* __restrict__ Cp, int M, int N, int K, int Kst,
    int64_t sA, int64_t sB, int64_t sC,
    const float* __restrict__ e0, const float* __restrict__ e1,
    const float* __restrict__ e2, const void* __restrict__ e3, int64_t sE) {
  constexpr int MF = BM / 32;
  constexpr int NF = BN / 32;
  constexpr int ASLOT = BM / 64;
  constexpr int BSLOT = BN / 64;
  constexpr int NL = ASLOT + BSLOT;
  constexpr int SBUF = (BM + BN) * 32;
  __shared__ short lds[D * SBUF];
  const int tid = threadIdx.x;

  // bijective XCD chunked swizzle (m204); requires nwg % 8 == 0
  const unsigned gx = gridDim.x, gy = gridDim.y;
  const unsigned nwg = gx * gy * gridDim.z;
  const unsigned lin = blockIdx.x + gx * (blockIdx.y + gy * blockIdx.z);
  const unsigned cs = nwg >> 3;
  const unsigned nl = (lin & 7) * cs + (lin >> 3);
  const unsigned bxs = nl % gx;
  const unsigned tmp = nl / gx;
  const unsigned bys = tmp % gy;
  const unsigned bz = tmp / gy;

  const int brow = bys * BM;
  const int bcol = bxs * BN;
  const short* Ab = A + bz * sA;
  const short* Bb = B + bz * sB;

  const int srow = ((tid >> 6) << 4) + (tid & 15);
  const int skc = ((tid >> 4) & 3) * 8;
  const short* gA[ASLOT];
  const short* gB[BSLOT];
#pragma unroll
  for (int s = 0; s < ASLOT; ++s)
    gA[s] = Ab + (int64_t)(brow + s * 64 + srow) * Kst + skc;
#pragma unroll
  for (int s = 0; s < BSLOT; ++s)
    gB[s] = Bb + (int64_t)(bcol + s * 64 + srow) * Kst + skc;

  const int lane = tid & 63, wid = tid >> 6;
  const int wr = wid >> 1, wc = wid & 1;

  f32x4 acc[MF][NF] = {};

  auto stage = [&](int buf, int k0) {
    short* d = lds + buf * SBUF;
#pragma unroll
    for (int s = 0; s < ASLOT; ++s)
      gload16(gA[s] + k0, d + s * 2048 + tid * 8);
#pragma unroll
    for (int s = 0; s < BSLOT; ++s)
      gload16(gB[s] + k0, d + BM * 32 + s * 2048 + tid * 8);
  };
  auto compute = [&](int buf) {
    const short* base = lds + buf * SBUF;
    bf16x8 af[MF], bfv[NF];
#pragma unroll
    for (int m = 0; m < MF; ++m)
      af[m] = *(const bf16x8*)(base + (wr * MF + m) * 512 + lane * 8);
#pragma unroll
    for (int n = 0; n < NF; ++n)
      bfv[n] = *(const bf16x8*)(base + BM * 32 + (wc * NF + n) * 512 + lane * 8);
#pragma unroll
    for (int m = 0; m < MF; ++m)
#pragma unroll
      for (int n = 0; n < NF; ++n)
        acc[m][n] = __builtin_amdgcn_mfma_f32_16x16x32_bf16(af[m], bfv[n],
                                                            acc[m][n], 0, 0, 0);
  };

  const int nst = K / 32;
#pragma unroll
  for (int d = 0; d < D - 1; ++d) stage(d, d * 32);
  for (int t = 0; t <= nst - D; ++t) {
    stage((t + D - 1) & (D - 1), (t + D - 1) * 32);
    waitv<(D - 1) * NL>();
    barrier_();
    compute(t & (D - 1));
    barrier_();
  }
  {
    int t = nst - D + 1;
    if constexpr (D >= 8) {
      waitv<6 * NL>(); barrier_(); compute(t & (D - 1)); barrier_(); ++t;
      waitv<5 * NL>(); barrier_(); compute(t & (D - 1)); barrier_(); ++t;
      waitv<4 * NL>(); barrier_(); compute(t & (D - 1)); barrier_(); ++t;
      waitv<3 * NL>(); barrier_(); compute(t & (D - 1)); barrier_(); ++t;
    }
    if constexpr (D >= 4) {
      waitv<2 * NL>(); barrier_(); compute(t & (D - 1)); barrier_(); ++t;
      waitv<1 * NL>(); barrier_(); compute(t & (D - 1)); barrier_(); ++t;
    }
    waitv<0>(); barrier_(); compute(t & (D - 1));
  }

  const int r0 = brow + wr * (BM / 2) + (lane >> 4) * 4;
  const int c0 = bcol + wc * (BN / 2) + (lane & 15);
#pragma unroll
  for (int m = 0; m < MF; ++m) {
#pragma unroll
    for (int j = 0; j < 4; ++j) {
      int row = r0 + m * 16 + j;
#pragma unroll
      for (int n = 0; n < NF; ++n) {
        int col = c0 + n * 16;
        float v = acc[m][n][j];
        int64_t idx = (int64_t)row * N + col;
        if (EPI == 0) {
          ((short*)Cp)[bz * sC + idx] = f2b(v);
        } else if (EPI == 1) {
          ((short*)Cp)[bz * sC + idx] = f2b(sigm(v));
        } else if (EPI == 2) {
          v = fmaxf(v, 0.0f);
          ((short*)Cp)[bz * sC + idx] = f2b(v * v);
        } else if (EPI == 3) {
          float r2 = v + e0[row] * e1[col] + e2[col];
          float xo = ((const float*)e3)[bz * sE + idx];
          ((float*)Cp)[bz * sC + idx] = xo * (1.0f + r2);
        } else if (EPI == 4) {
          float* XC = (float*)Cp;
          XC[idx] = XC[idx] + lif4(v);
        } else if (EPI == 5) {
          float* XC = (float*)Cp;
          float srr = b2f(((const short*)e3)[idx]);
          float nv = XC[idx] + lif4(v * srr);
          XC[idx] = nv;
          int tt = row & 511;
          if (tt >= 256) {  // fused rtok emit (b, t-256, col) bf16
            short* rtok = (short*)(void*)const_cast<float*>(e1);
            rtok[(((int64_t)(row >> 9)) * 256 + (tt - 256)) * 1024 + col] =
                f2b(nv);
          }
        } else if (EPI == 6) {
          ((short*)Cp)[bz * sC + idx] = f2b(bz == 2 ? sigm(v) : v);
        }
      }
    }
  }
}

// ---------------- launch ----------------
extern "C" void kernel_launch(void* const* d_in, const int* in_sizes, int n_in,
                              void* d_out, int out_size, void* d_ws,
                              size_t ws_size, hipStream_t stream) {
  const float* x   = (const float*)d_in[0];
  const float* rt  = (const float*)d_in[1];
  const float* td  = (const float*)d_in[2];
  const float* tf  = (const float*)d_in[3];
  const float* tmk = (const float*)d_in[4];
  const float* tmv = (const float*)d_in[5];
  const float* tmr = (const float*)d_in[6];
  const float* Wk  = (const float*)d_in[7];
  const float* Wv  = (const float*)d_in[8];
  const float* Wr  = (const float*)d_in[9];
  const float* Wo  = (const float*)d_in[10];
  const float* cmk = (const float*)d_in[11];
  const float* cmr = (const float*)d_in[12];
  const float* Wck = (const float*)d_in[13];
  const float* Wcv = (const float*)d_in[14];
  const float* Wcr = (const float*)d_in[15];
  const float* Wrm = (const float*)d_in[16];
  const float* brm = (const float*)d_in[17];
  const float* Wam = (const float*)d_in[18];
  const float* bam = (const float*)d_in[19];
  float* out = (float*)d_out;

  const size_t MB = 1ull << 20;
  uint8_t* W8 = (uint8_t*)d_ws;
  // Memory map (MB offsets), phase-ordered reuse:
  float* XC   = (float*)(W8);                        // 0-16 residual f32
  short* S1   = (short*)(W8 + 24 * MB);              // 24-32 xk / SRY / SRR
  short* S2   = (short*)(W8 + 32 * MB);              // 32-40 xv / xk2 / rtok,Mt
  short* S3   = (short*)(W8 + 40 * MB);              // 40-48 xr / xr2 / bWck
  short* bWcv = (short*)(W8 + 48 * MB);              // 48-56
  short* bWk  = (short*)(W8 + 56 * MB);              // 56-62 bWk,bWv,bWr contig
  short* bWo  = (short*)(W8 + 62 * MB);
  short* bWcr = (short*)(W8 + 64 * MB);
  short* bWrm = (short*)(W8 + 66 * MB);              // 0.5 MB
  short* bWam = (short*)(W8 + 66 * MB + 512 * 1024); // 0.5 MB
  short* KK   = (short*)(W8 + 67 * MB);              // 67-75
  short* VV   = (short*)(W8 + 75 * MB);              // 75-83
  short* RR   = (short*)(W8 + 83 * MB);              // 83-91
  float* Ca   = (float*)(W8 + 91 * MB);              // wkv temps 91-97
  float* Da   = (float*)(W8 + 92 * MB);
  float* Qa   = (float*)(W8 + 93 * MB);
  float* Aa   = (float*)(W8 + 94 * MB);
  float* Ba   = (float*)(W8 + 95 * MB);
  float* Pa   = (float*)(W8 + 96 * MB);
  short* SRY  = S1;
  short* xk2  = S2;
  short* xr2  = S3;
  short* SRR  = S1;                                  // written step 6
  short* bWck = S3;                                  // after SRR GEMM
  short* H16  = KK;                                  // 67-99 (32 MB)
  short* rtok = S2;                                  // 32-36 (tail)
  short* Mt   = (short*)(W8 + 36 * MB);              // 36-37 (tail)
  float* Sb   = (float*)(W8 + 99 * MB);              // 4 KB, aliases nothing

  dim3 blk(256);

  // 0) ALL weight conversions + Wam row-sum in one launch
  cvt_all<<<5120, blk, 0, stream>>>(Wk, Wv, Wr, Wo, Wcr, Wcv, Wrm, Wam,
                                    bWk, bWk + 1048576, bWk + 2097152, bWo,
                                    bWcr, bWcv, bWrm, bWam, Sb);

  // 1) FUSED concat + ln1 + time-mix blends -> XC, S1, S2, S3
  ln_mix3<<<TB_ * TT_, blk, 0, stream>>>(x, rt, tmk, tmv, tmr, XC, S1, S2, S3);

  // 2) fused z=3 time-mix: KK = xk*Wk^T, VV = xv*Wv^T, RR = sigm(xr*Wr^T)
  //    (grid 768 = 3 blk/CU, D=2)
  gemm_bf16<128, 128, 6, 2, 3><<<dim3(8, 32, 3), blk, 0, stream>>>(
      S1, bWk, KK, 4096, 1024, 1024, 1024, 4194304, 1048576, 4194304,
      nullptr, nullptr, nullptr, nullptr, 0);
  // 3) wkv chunked scan -> SRY (=S1)
  wkv_p1<<<WKV_NCH * TB_ * 4, blk, 0, stream>>>(td, KK, VV, Ca, Da, Qa);
  wkv_p2<<<32, blk, 0, stream>>>(td, Ca, Da, Qa, Aa, Ba, Pa);
  wkv_p3<<<WKV_NCH * TB_ * 4, blk, 0, stream>>>(td, tf, KK, VV, RR, SRY,
                                                Aa, Ba, Pa);
  // 4) att: XC += lif(SRY*Wo^T)   (grid 256 = 1 blk/CU -> D=8, measured best)
  gemm_bf16<128, 128, 4, 8, 1><<<dim3(8, 32, 1), blk, 0, stream>>>(
      SRY, bWo, XC, 4096, 1024, 1024, 1024, 0, 0, 0,
      nullptr, nullptr, nullptr, nullptr, 0);
  // 5) fused ln2+mix2 -> xk2(S2), xr2(S3)
  ln_mix2<<<TB_ * TT_, blk, 0, stream>>>(XC, cmk, cmr, xk2, xr2);
  // 6) SRR = sigm(xr2*Wcr^T) -> S1   (D=8)
  gemm_bf16<128, 128, 1, 8, 1><<<dim3(8, 32, 1), blk, 0, stream>>>(
      xr2, bWcr, SRR, 4096, 1024, 1024, 1024, 0, 0, 0,
      nullptr, nullptr, nullptr, nullptr, 0);
  // 7) Wck -> bf16 into now-dead xr2 slot
  cvt_b<<<2048, blk, 0, stream>>>(Wck, bWck);
  // 8) H = relu^2(xk2*Wck^T) -> H16 (grid 1024 = 4 blk/CU, D=2)
  gemm_bf16<128, 128, 2, 2, 4><<<dim3(32, 32, 1), blk, 0, stream>>>(
      xk2, bWck, H16, 4096, 4096, 1024, 1024, 0, 0, 0,
      nullptr, nullptr, nullptr, nullptr, 0);
  // 9) XC += lif(SRR*(H*Wcv^T)); rows t>=256 also emit rtok bf16 (D=8)
  gemm_bf16<128, 128, 5, 8, 1><<<dim3(8, 32, 1), blk, 0, stream>>>(
      H16, bWcv, XC, 4096, 1024, 4096, 4096, 0, 0, 0,
      nullptr, (const float*)rtok, nullptr, SRR, 0);
  // 10) tail: Mt = Wrm x rtok^T per batch; out = xo*(1+Mt*Wam^T+brm*S+bam)
  gemm_bf16<64, 64, 0, 2, 2><<<dim3(4, 4, 8), blk, 0, stream>>>(
      bWrm, rtok, Mt, 256, 256, 1024, 1024, 0, (int64_t)256 * 1024,
      (int64_t)256 * 256, nullptr, nullptr, nullptr, nullptr, 0);
  gemm_bf16<64, 64, 3, 2, 2><<<dim3(16, 4, 8), blk, 0, stream>>>(
      Mt, bWam, out, 256, 1024, 256, 256, (int64_t)256 * 256, 0,
      (int64_t)256 * 1024, brm, Sb, bam, XC, (int64_t)512 * 1024);
}

// Round 16
// 328.571 us; speedup vs baseline: 1.0591x; 1.0432x over previous
//
#include <hip/hip_runtime.h>
#include <hip/hip_bf16.h>
#include <math.h>
#include <stdint.h>

// B=8, P1=256 -> T=512 concat rows, C=1024, H=4096
#define TB_ 8
#define TT_ 512
#define TC_ 1024
#define WKV_NCH 32
#define WKV_L 16

typedef __attribute__((ext_vector_type(8))) short bf16x8;
typedef __attribute__((ext_vector_type(4))) short s16x4;
typedef __attribute__((ext_vector_type(4))) float f32x4;

__device__ __forceinline__ float b2f(short u) {
  union { unsigned int i; float f; } x;
  x.i = ((unsigned int)(unsigned short)u) << 16;
  return x.f;
}
__device__ __forceinline__ short f2b(float f) {
  __hip_bfloat16 h = __float2bfloat16(f);  // RNE
  return __builtin_bit_cast(short, h);
}
__device__ __forceinline__ float sigm(float x) { return 1.0f / (1.0f + expf(-x)); }

__device__ __forceinline__ float lif4(float a) {
  float v = 0.0f, acc = 0.0f;
#pragma unroll
  for (int i = 0; i < 4; ++i) {
    v += (a - v) * 0.5f;
    float s = (v >= 1.0f) ? 1.0f : 0.0f;
    acc += s;
    v *= (1.0f - s);
  }
  return acc * 0.25f;
}

__device__ __forceinline__ void gload16(const void* g, void* l) {
  __builtin_amdgcn_global_load_lds(
      (__attribute__((address_space(1))) void*)(g),
      (__attribute__((address_space(3))) void*)(l), 16, 0, 0);
}

template <int N>
__device__ __forceinline__ void waitv() {
  if constexpr (N == 0)  asm volatile("s_waitcnt vmcnt(0)" ::: "memory");
  else if constexpr (N == 2)  asm volatile("s_waitcnt vmcnt(2)" ::: "memory");
  else if constexpr (N == 4)  asm volatile("s_waitcnt vmcnt(4)" ::: "memory");
  else if constexpr (N == 8)  asm volatile("s_waitcnt vmcnt(8)" ::: "memory");
  else if constexpr (N == 12) asm volatile("s_waitcnt vmcnt(12)" ::: "memory");
  else static_assert(N == 0, "unsupported vmcnt");
}
__device__ __forceinline__ void barrier_() {
  asm volatile("s_barrier" ::: "memory");
}

// ---------------- elementwise kernels ----------------

// FUSED concat + ln1 + time-mix blends (one 256-thr block per row).
__global__ __launch_bounds__(256) void ln_mix3(
    const float* __restrict__ x, const float* __restrict__ rt,
    const float* __restrict__ tmk, const float* __restrict__ tmv,
    const float* __restrict__ tmr, float* __restrict__ xc,
    short* __restrict__ xk, short* __restrict__ xv, short* __restrict__ xr) {
  __shared__ float red[256];
  int row = blockIdx.x;
  int t = row & 511, b = row >> 9;
  int tid = threadIdx.x;
  const float* src = (t < 256) ? x + (int64_t)(b * 256 + t) * TC_
                               : rt + (int64_t)(t - 256) * TC_;
  float4 v = ((const float4*)src)[tid];
  ((float4*)(xc + (int64_t)row * TC_))[tid] = v;
  red[tid] = v.x + v.y + v.z + v.w;
  __syncthreads();
  for (int off = 128; off > 0; off >>= 1) {
    if (tid < off) red[tid] += red[tid + off];
    __syncthreads();
  }
  float mean = red[0] * (1.0f / 1024.0f);
  __syncthreads();
  float dx = v.x - mean, dy = v.y - mean, dz = v.z - mean, dw = v.w - mean;
  red[tid] = dx * dx + dy * dy + dz * dz + dw * dw;
  __syncthreads();
  for (int off = 128; off > 0; off >>= 1) {
    if (tid < off) red[tid] += red[tid + off];
    __syncthreads();
  }
  float rs = 1.0f / sqrtf(red[0] * (1.0f / 1024.0f) + 1e-6f);
  float c0 = dx * rs, c1 = dy * rs, c2 = dz * rs, c3 = dw * rs;
  float p0 = 0.f, p1 = 0.f, p2 = 0.f, p3 = 0.f;
  if (t > 0) {  // block-uniform
    int tp = t - 1;
    const float* srcp = (tp < 256) ? x + (int64_t)(b * 256 + tp) * TC_
                                   : rt + (int64_t)(tp - 256) * TC_;
    __syncthreads();
    float4 w4 = ((const float4*)srcp)[tid];
    red[tid] = w4.x + w4.y + w4.z + w4.w;
    __syncthreads();
    for (int off = 128; off > 0; off >>= 1) {
      if (tid < off) red[tid] += red[tid + off];
      __syncthreads();
    }
    float meanp = red[0] * (1.0f / 1024.0f);
    __syncthreads();
    float ex = w4.x - meanp, ey = w4.y - meanp, ez = w4.z - meanp,
          ew = w4.w - meanp;
    red[tid] = ex * ex + ey * ey + ez * ez + ew * ew;
    __syncthreads();
    for (int off = 128; off > 0; off >>= 1) {
      if (tid < off) red[tid] += red[tid + off];
      __syncthreads();
    }
    float rsp = 1.0f / sqrtf(red[0] * (1.0f / 1024.0f) + 1e-6f);
    p0 = ex * rsp; p1 = ey * rsp; p2 = ez * rsp; p3 = ew * rsp;
  }
  int c = tid * 4;
  int64_t o = (int64_t)row * TC_ + c;
  float m0, m1, m2, m3;
  s16x4 ov;
  m0 = tmk[c]; m1 = tmk[c + 1]; m2 = tmk[c + 2]; m3 = tmk[c + 3];
  ov.x = f2b(c0 * m0 + p0 * (1.0f - m0));
  ov.y = f2b(c1 * m1 + p1 * (1.0f - m1));
  ov.z = f2b(c2 * m2 + p2 * (1.0f - m2));
  ov.w = f2b(c3 * m3 + p3 * (1.0f - m3));
  *(s16x4*)(xk + o) = ov;
  m0 = tmv[c]; m1 = tmv[c + 1]; m2 = tmv[c + 2]; m3 = tmv[c + 3];
  ov.x = f2b(c0 * m0 + p0 * (1.0f - m0));
  ov.y = f2b(c1 * m1 + p1 * (1.0f - m1));
  ov.z = f2b(c2 * m2 + p2 * (1.0f - m2));
  ov.w = f2b(c3 * m3 + p3 * (1.0f - m3));
  *(s16x4*)(xv + o) = ov;
  m0 = tmr[c]; m1 = tmr[c + 1]; m2 = tmr[c + 2]; m3 = tmr[c + 3];
  ov.x = f2b(c0 * m0 + p0 * (1.0f - m0));
  ov.y = f2b(c1 * m1 + p1 * (1.0f - m1));
  ov.z = f2b(c2 * m2 + p2 * (1.0f - m2));
  ov.w = f2b(c3 * m3 + p3 * (1.0f - m3));
  *(s16x4*)(xr + o) = ov;
}

// fused ln2 + channel-mix blend (same recompute pattern).
__global__ __launch_bounds__(256) void ln_mix2(const float* __restrict__ xc,
                                               const float* __restrict__ cmk,
                                               const float* __restrict__ cmr,
                                               short* __restrict__ xk,
                                               short* __restrict__ xr) {
  __shared__ float red[256];
  int row = blockIdx.x;
  int t = row & 511;
  int tid = threadIdx.x;
  float4 v = ((const float4*)(xc + (int64_t)row * TC_))[tid];
  red[tid] = v.x + v.y + v.z + v.w;
  __syncthreads();
  for (int off = 128; off > 0; off >>= 1) {
    if (tid < off) red[tid] += red[tid + off];
    __syncthreads();
  }
  float mean = red[0] * (1.0f / 1024.0f);
  __syncthreads();
  float dx = v.x - mean, dy = v.y - mean, dz = v.z - mean, dw = v.w - mean;
  red[tid] = dx * dx + dy * dy + dz * dz + dw * dw;
  __syncthreads();
  for (int off = 128; off > 0; off >>= 1) {
    if (tid < off) red[tid] += red[tid + off];
    __syncthreads();
  }
  float rs = 1.0f / sqrtf(red[0] * (1.0f / 1024.0f) + 1e-6f);
  float c0 = dx * rs, c1 = dy * rs, c2 = dz * rs, c3 = dw * rs;
  float p0 = 0.f, p1 = 0.f, p2 = 0.f, p3 = 0.f;
  if (t > 0) {
    __syncthreads();
    float4 w4 = ((const float4*)(xc + (int64_t)(row - 1) * TC_))[tid];
    red[tid] = w4.x + w4.y + w4.z + w4.w;
    __syncthreads();
    for (int off = 128; off > 0; off >>= 1) {
      if (tid < off) red[tid] += red[tid + off];
      __syncthreads();
    }
    float meanp = red[0] * (1.0f / 1024.0f);
    __syncthreads();
    float ex = w4.x - meanp, ey = w4.y - meanp, ez = w4.z - meanp,
          ew = w4.w - meanp;
    red[tid] = ex * ex + ey * ey + ez * ez + ew * ew;
    __syncthreads();
    for (int off = 128; off > 0; off >>= 1) {
      if (tid < off) red[tid] += red[tid + off];
      __syncthreads();
    }
    float rsp = 1.0f / sqrtf(red[0] * (1.0f / 1024.0f) + 1e-6f);
    p0 = ex * rsp; p1 = ey * rsp; p2 = ez * rsp; p3 = ew * rsp;
  }
  int c = tid * 4;
  float k0 = cmk[c], k1 = cmk[c + 1], k2 = cmk[c + 2], k3 = cmk[c + 3];
  float r0 = cmr[c], r1 = cmr[c + 1], r2 = cmr[c + 2], r3 = cmr[c + 3];
  s16x4 ok, orr;
  ok.x = f2b(c0 * k0 + p0 * (1.0f - k0));
  ok.y = f2b(c1 * k1 + p1 * (1.0f - k1));
  ok.z = f2b(c2 * k2 + p2 * (1.0f - k2));
  ok.w = f2b(c3 * k3 + p3 * (1.0f - k3));
  orr.x = f2b(c0 * r0 + p0 * (1.0f - r0));
  orr.y = f2b(c1 * r1 + p1 * (1.0f - r1));
  orr.z = f2b(c2 * r2 + p2 * (1.0f - r2));
  orr.w = f2b(c3 * r3 + p3 * (1.0f - r3));
  *(s16x4*)(xk + (int64_t)row * TC_ + c) = ok;
  *(s16x4*)(xr + (int64_t)row * TC_ + c) = orr;
}

// f32 -> bf16, 8 elems/thread
__global__ __launch_bounds__(256) void cvt_b(const float* __restrict__ src,
                                             short* __restrict__ dst) {
  int64_t i = (int64_t)(blockIdx.x * 256 + threadIdx.x) * 8;
  float4 a = *(const float4*)(src + i);
  float4 b = *(const float4*)(src + i + 4);
  bf16x8 o;
  o[0] = f2b(a.x); o[1] = f2b(a.y); o[2] = f2b(a.z); o[3] = f2b(a.w);
  o[4] = f2b(b.x); o[5] = f2b(b.y); o[6] = f2b(b.z); o[7] = f2b(b.w);
  *(bf16x8*)(dst + i) = o;
}

// rtok rows (per b: rows 256..511 of XC) f32 -> bf16 contiguous (B,256,C)
__global__ __launch_bounds__(256) void cvt_rtok(const float* __restrict__ xc,
                                                short* __restrict__ dst) {
  int i = blockIdx.x * 256 + threadIdx.x;  // short8 idx
  int b = i >> 15;
  int rem = i & 32767;
  const float* s = xc + (int64_t)b * 524288 + 262144 + (int64_t)rem * 8;
  float4 a = *(const float4*)s;
  float4 c = *(const float4*)(s + 4);
  bf16x8 o;
  o[0] = f2b(a.x); o[1] = f2b(a.y); o[2] = f2b(a.z); o[3] = f2b(a.w);
  o[4] = f2b(c.x); o[5] = f2b(c.y); o[6] = f2b(c.z); o[7] = f2b(c.w);
  *(bf16x8*)(dst + (int64_t)i * 8) = o;
}

// ONE launch: convert 8 weight arrays f32->bf16 + fused Wam row-sum.
__global__ __launch_bounds__(256) void cvt_all(
    const float* __restrict__ Wk, const float* __restrict__ Wv,
    const float* __restrict__ Wr, const float* __restrict__ Wo,
    const float* __restrict__ Wcr, const float* __restrict__ Wcv,
    const float* __restrict__ Wrm, const float* __restrict__ Wam,
    short* __restrict__ bWk, short* __restrict__ bWv, short* __restrict__ bWr,
    short* __restrict__ bWo, short* __restrict__ bWcr, short* __restrict__ bWcv,
    short* __restrict__ bWrm, short* __restrict__ bWam,
    float* __restrict__ S) {
  int bid = blockIdx.x;
  if (bid >= 4864) {
    int row = (bid - 4864) * 4 + (threadIdx.x >> 6);
    int lane = threadIdx.x & 63;
    float4 v = ((const float4*)(Wam + (int64_t)row * 256))[lane];
    float s = v.x + v.y + v.z + v.w;
    for (int off = 32; off > 0; off >>= 1) s += __shfl_down(s, off);
    if (lane == 0) S[row] = s;
    return;
  }
  const float* src; short* dst; int base;
  if (bid < 512)       { src = Wk;  dst = bWk;  base = bid; }
  else if (bid < 1024) { src = Wv;  dst = bWv;  base = bid - 512; }
  else if (bid < 1536) { src = Wr;  dst = bWr;  base = bid - 1024; }
  else if (bid < 2048) { src = Wo;  dst = bWo;  base = bid - 1536; }
  else if (bid < 2560) { src = Wcr; dst = bWcr; base = bid - 2048; }
  else if (bid < 4608) { src = Wcv; dst = bWcv; base = bid - 2560; }
  else if (bid < 4736) { src = Wrm; dst = bWrm; base = bid - 4608; }
  else                 { src = Wam; dst = bWam; base = bid - 4736; }
  int64_t i = ((int64_t)base * 256 + threadIdx.x) * 8;
  float4 a = *(const float4*)(src + i);
  float4 b = *(const float4*)(src + i + 4);
  bf16x8 o;
  o[0] = f2b(a.x); o[1] = f2b(a.y); o[2] = f2b(a.z); o[3] = f2b(a.w);
  o[4] = f2b(b.x); o[5] = f2b(b.y); o[6] = f2b(b.z); o[7] = f2b(b.w);
  *(bf16x8*)(dst + i) = o;
}

// ---------------- wkv chunked parallel scan ----------------
__global__ __launch_bounds__(256) void wkv_p1(const float* __restrict__ td,
                                              const short* __restrict__ K,
                                              const short* __restrict__ V,
                                              float* __restrict__ Ca,
                                              float* __restrict__ Da,
                                              float* __restrict__ Qa) {
  int bx = blockIdx.x;
  int ch = bx >> 5;
  int b = (bx >> 2) & 7;
  int c = (bx & 3) * 256 + threadIdx.x;
  float w = -expf(td[c]);
  float aa = 0.0f, bb = 0.0f, pp = -1e38f;
  int64_t base = ((int64_t)b * TT_ + ch * WKV_L) * TC_ + c;
#pragma unroll
  for (int t = 0; t < WKV_L; ++t) {
    int64_t o = base + (int64_t)t * TC_;
    float kt = b2f(K[o]), vt = b2f(V[o]);
    float ww2 = pp + w;
    float p2 = fmaxf(ww2, kt);
    float e1 = expf(ww2 - p2);
    float e2 = expf(kt - p2);
    aa = e1 * aa + e2 * vt;
    bb = e1 * bb + e2;
    pp = p2;
  }
  int idx = ch * 8192 + b * 1024 + c;
  Ca[idx] = aa; Da[idx] = bb; Qa[idx] = pp;
}

__global__ __launch_bounds__(256) void wkv_p2(const float* __restrict__ td,
                                              const float* __restrict__ Ca,
                                              const float* __restrict__ Da,
                                              const float* __restrict__ Qa,
                                              float* __restrict__ Aa,
                                              float* __restrict__ Ba,
                                              float* __restrict__ Pa) {
  int i = blockIdx.x * 256 + threadIdx.x;
  int c = i & (TC_ - 1);
  float wL = -expf(td[c]) * (float)WKV_L;
  float aa = 0.0f, bb = 0.0f, pp = -1e38f;
#pragma unroll 4
  for (int ch = 0; ch < WKV_NCH; ++ch) {
    int idx = ch * 8192 + i;
    Aa[idx] = aa; Ba[idx] = bb; Pa[idx] = pp;
    float ppw = pp + wL;
    float q = Qa[idx];
    float p2 = fmaxf(ppw, q);
    float ea = expf(ppw - p2);
    float eb = expf(q - p2);
    aa = aa * ea + Ca[idx] * eb;
    bb = bb * ea + Da[idx] * eb;
    pp = p2;
  }
}

__global__ __launch_bounds__(256) void wkv_p3(const float* __restrict__ td,
                                              const float* __restrict__ tf,
                                              const short* __restrict__ K,
                                              const short* __restrict__ V,
                                              const short* __restrict__ SR,
                                              short* __restrict__ SRY,
                                              const float* __restrict__ Aa,
                                              const float* __restrict__ Ba,
                                              const float* __restrict__ Pa) {
  int bx = blockIdx.x;
  int ch = bx >> 5;
  int b = (bx >> 2) & 7;
  int c = (bx & 3) * 256 + threadIdx.x;
  float w = -expf(td[c]);
  float u = tf[c];
  int idx = ch * 8192 + b * 1024 + c;
  float aa = Aa[idx], bb = Ba[idx], pp = Pa[idx];
  int64_t base = ((int64_t)b * TT_ + ch * WKV_L) * TC_ + c;
#pragma unroll
  for (int t = 0; t < WKV_L; ++t) {
    int64_t o = base + (int64_t)t * TC_;
    float kt = b2f(K[o]), vt = b2f(V[o]);
    float ww = u + kt;
    float p = fmaxf(pp, ww);
    float E1 = expf(pp - p);
    float E2 = expf(ww - p);
    float y = (E1 * aa + E2 * vt) / (E1 * bb + E2);
    SRY[o] = f2b(y * b2f(SR[o]));
    float ww2 = pp + w;
    float p2 = fmaxf(ww2, kt);
    float e1 = expf(ww2 - p2);
    float e2 = expf(kt - p2);
    aa = e1 * aa + e2 * vt;
    bb = e1 * bb + e2;
    pp = p2;
  }
}

// ---------------- 4-phase interleaved MFMA GEMM (1 blk/CU shapes) -------
// 128x128 tile, 8 waves (512 thr, 2/SIMD), BK=64, double-buffered LDS in
// MFMA lane order. Per K-tile: 4 phases, each {ds_read sub-frags; issue 1
// stage chunk; 4 MFMA; [counted vmcnt]; s_barrier}. With 2 waves/SIMD in a
// phase, one wave's ds_reads overlap the other's MFMAs (the overlap the
// lockstep 2-barrier loop provably lacked at 1 wave/SIMD, MfmaUtil 15%).
// Stage issue order per tile: A-k0, B-k0, A-k1, B-k1 (FIFO): waitv<2> at
// P1 retires own A-k1/B-k1 (read in P2/P3); waitv<2> at P3 retires next
// tile's A-k0/B-k0 (read at next P0); each wait precedes a barrier.
// EPI: 1 sigmoid bf16; 4 XC += lif4(acc); 5 XC += lif4(acc * srr(e3)).
template <int EPI>
__global__ __launch_bounds__(512, 1) void gemm4p(
    const short* __restrict__ A, const short* __restrict__ B,
    void* __restrict__ Cp, int M, int N, int K, int Kst,
    const float* __restrict__ e0, const float* __restrict__ e1,
    const float* __restrict__ e2, const void* __restrict__ e3) {
  __shared__ short lds[2 * 32768];  // buf: [Ak0 8192][Ak1 8192][Bk0][Bk1]
  const int tid = threadIdx.x;

  // bijective XCD chunked swizzle; grid 256 -> nwg%8==0
  const unsigned gx = gridDim.x, gy = gridDim.y;
  const unsigned nwg = gx * gy;
  const unsigned lin = blockIdx.x + gx * blockIdx.y;
  const unsigned cs = nwg >> 3;
  const unsigned nl = (lin & 7) * cs + (lin >> 3);
  const unsigned bxs = nl % gx;
  const unsigned bys = nl / gx;

  const int brow = bys * 128;
  const int bcol = bxs * 128;

  // staging: thread stages 1 chunk per phase; slot tid in 8KB sub-buffer
  const int srow = ((tid >> 6) << 4) + (tid & 15);  // 0..127
  const int skc = ((tid >> 4) & 3) * 8;
  const short* gA = A + (int64_t)(brow + srow) * Kst + skc;
  const short* gB = B + (int64_t)(bcol + srow) * Kst + skc;

  const int lane = tid & 63, wid = tid >> 6;  // 8 waves
  const int wr = wid >> 2, wc = wid & 3;      // 2x4 -> wave owns 64x32

  f32x4 acc[4][2] = {};

#define RD_A(rb, kh, m) \
  (*(const bf16x8*)(lds + (rb) * 32768 + (kh) * 8192 + (wr * 4 + (m)) * 512 + lane * 8))
#define RD_B(rb, kh, n) \
  (*(const bf16x8*)(lds + (rb) * 32768 + 16384 + (kh) * 8192 + (wc * 2 + (n)) * 512 + lane * 8))
#define ST_A(sb, kh, kt) \
  gload16(gA + (kt) * 64 + (kh) * 32, lds + (sb) * 32768 + (kh) * 8192 + tid * 8)
#define ST_B(sb, kh, kt) \
  gload16(gB + (kt) * 64 + (kh) * 32, lds + (sb) * 32768 + 16384 + (kh) * 8192 + tid * 8)
#define MM(am, bn, i, j) \
  acc[i][j] = __builtin_amdgcn_mfma_f32_16x16x32_bf16(am, bn, acc[i][j], 0, 0, 0)

  const int nt = K / 64;
  // prologue: stage tile 0 (order A-k0, B-k0, A-k1, B-k1)
  ST_A(0, 0, 0); ST_B(0, 0, 0); ST_A(0, 1, 0); ST_B(0, 1, 0);
  waitv<2>();   // A-k0, B-k0 resident
  barrier_();

  for (int t = 0; t < nt - 1; ++t) {
    const int rb = t & 1, sb = rb ^ 1, kn = t + 1;
    // P0: k0, m01
    {
      bf16x8 a0 = RD_A(rb, 0, 0), a1 = RD_A(rb, 0, 1);
      bf16x8 b0 = RD_B(rb, 0, 0), b1 = RD_B(rb, 0, 1);
      ST_A(sb, 0, kn);
      MM(a0, b0, 0, 0); MM(a0, b1, 0, 1); MM(a1, b0, 1, 0); MM(a1, b1, 1, 1);
      barrier_();
      // P1: k0, m23 (b0,b1 still valid register copies)
      bf16x8 a2 = RD_A(rb, 0, 2), a3 = RD_A(rb, 0, 3);
      ST_B(sb, 0, kn);
      MM(a2, b0, 2, 0); MM(a2, b1, 2, 1); MM(a3, b0, 3, 0); MM(a3, b1, 3, 1);
      waitv<2>();  // retire own A-k1, B-k1 of tile t
      barrier_();
    }
    // P2: k1, m01
    {
      bf16x8 a0 = RD_A(rb, 1, 0), a1 = RD_A(rb, 1, 1);
      bf16x8 b0 = RD_B(rb, 1, 0), b1 = RD_B(rb, 1, 1);
      ST_A(sb, 1, kn);
      MM(a0, b0, 0, 0); MM(a0, b1, 0, 1); MM(a1, b0, 1, 0); MM(a1, b1, 1, 1);
      barrier_();
      // P3: k1, m23
      bf16x8 a2 = RD_A(rb, 1, 2), a3 = RD_A(rb, 1, 3);
      ST_B(sb, 1, kn);
      MM(a2, b0, 2, 0); MM(a2, b1, 2, 1); MM(a3, b0, 3, 0); MM(a3, b1, 3, 1);
      waitv<2>();  // retire tile t+1's A-k0, B-k0
      barrier_();
    }
  }
  // final tile: everything resident after drain
  {
    waitv<0>();
    barrier_();
    const int rb = (nt - 1) & 1;
#pragma unroll
    for (int kh = 0; kh < 2; ++kh) {
      bf16x8 a0 = RD_A(rb, kh, 0), a1 = RD_A(rb, kh, 1);
      bf16x8 a2 = RD_A(rb, kh, 2), a3 = RD_A(rb, kh, 3);
      bf16x8 b0 = RD_B(rb, kh, 0), b1 = RD_B(rb, kh, 1);
      MM(a0, b0, 0, 0); MM(a0, b1, 0, 1); MM(a1, b0, 1, 0); MM(a1, b1, 1, 1);
      MM(a2, b0, 2, 0); MM(a2, b1, 2, 1); MM(a3, b0, 3, 0); MM(a3, b1, 3, 1);
    }
  }
#undef RD_A
#undef RD_B
#undef ST_A
#undef ST_B
#undef MM

  const int r0 = brow + wr * 64 + (lane >> 4) * 4;
  const int c0 = bcol + wc * 32 + (lane & 15);
#pragma unroll
  for (int m = 0; m < 4; ++m) {
#pragma unroll
    for (int j = 0; j < 4; ++j) {
      int row = r0 + m * 16 + j;
#pragma unroll
      for (int n = 0; n < 2; ++n) {
        int col = c0 + n * 16;
        float v = acc[m][n][j];
        int64_t idx = (int64_t)row * N + col;
        if (EPI == 1) {
          ((short*)Cp)[idx] = f2b(sigm(v));
        } else if (EPI == 4) {
          float* XC = (float*)Cp;
          XC[idx] = XC[idx] + lif4(v);
        } else if (EPI == 5) {
          float* XC = (float*)Cp;
          float srr = b2f(((const short*)e3)[idx]);
          XC[idx] = XC[idx] + lif4(v * srr);
        }
      }
    }
  }
}

// ---------------- LDS MFMA GEMM (2-barrier path: tmix, H, tails) --------
template <int BM, int BN, int EPI, int D, int MINW>
__global__ __launch_bounds__(256, MINW) void gemm_bf16(
    const short* __restrict__ A, const short* __restrict__ B,
    void* __restrict__ Cp, int M, int N, int K, int Kst,
    int64_t sA, int64_t sB, int64_t sC,
    const float* __restrict__ e0, const float* __restrict__ e1,
    const float* __restrict__ e2, const void* __restrict__ e3, int64_t sE) {
  constexpr int MF = BM / 32;
  constexpr int NF = BN / 32;
  constexpr int ASLOT = BM / 64;
  constexpr int BSLOT = BN / 64;
  constexpr int NL = ASLOT + BSLOT;
  constexpr int SBUF = (BM + BN) * 32;
  __shared__ short lds[D * SBUF];
  const int tid = threadIdx.x;

  const unsigned gx = gridDim.x, gy = gridDim.y;
  const unsigned nwg = gx * gy * gridDim.z;
  const unsigned lin = blockIdx.x + gx * (blockIdx.y + gy * blockIdx.z);
  const unsigned cs = nwg >> 3;
  const unsigned nl = (lin & 7) * cs + (lin >> 3);
  const unsigned bxs = nl % gx;
  const unsigned tmp = nl / gx;
  const unsigned bys = tmp % gy;
  const unsigned bz = tmp / gy;

  const int brow = bys * BM;
  const int bcol = bxs * BN;
  const short* Ab = A + bz * sA;
  const short* Bb = B + bz * sB;

  const int srow = ((tid >> 6) << 4) + (tid & 15);
  const int skc = ((tid >> 4) & 3) * 8;
  const short* gA[ASLOT];
  const short* gB[BSLOT];
#pragma unroll
  for (int s = 0; s < ASLOT; ++s)
    gA[s] = Ab + (int64_t)(brow + s * 64 + srow) * Kst + skc;
#pragma unroll
  for (int s = 0; s < BSLOT; ++s)
    gB[s] = Bb + (int64_t)(bcol + s * 64 + srow) * Kst + skc;

  const int lane = tid & 63, wid = tid >> 6;
  const int wr = wid >> 1, wc = wid & 1;

  f32x4 acc[MF][NF] = {};

  auto stage = [&](int buf, int k0) {
    short* d = lds + buf * SBUF;
#pragma unroll
    for (int s = 0; s < ASLOT; ++s)
      gload16(gA[s] + k0, d + s * 2048 + tid * 8);
#pragma unroll
    for (int s = 0; s < BSLOT; ++s)
      gload16(gB[s] + k0, d + BM * 32 + s * 2048 + tid * 8);
  };
  auto compute = [&](int buf) {
    const short* base = lds + buf * SBUF;
    bf16x8 af[MF], bfv[NF];
#pragma unroll
    for (int m = 0; m < MF; ++m)
      af[m] = *(const bf16x8*)(base + (wr * MF + m) * 512 + lane * 8);
#pragma unroll
    for (int n = 0; n < NF; ++n)
      bfv[n] = *(const bf16x8*)(base + BM * 32 + (wc * NF + n) * 512 + lane * 8);
#pragma unroll
    for (int m = 0; m < MF; ++m)
#pragma unroll
      for (int n = 0; n < NF; ++n)
        acc[m][n] = __builtin_amdgcn_mfma_f32_16x16x32_bf16(af[m], bfv[n],
                                                            acc[m][n], 0, 0, 0);
  };

  const int nst = K / 32;
#pragma unroll
  for (int d = 0; d < D - 1; ++d) stage(d, d * 32);
  for (int t = 0; t <= nst - D; ++t) {
    stage((t + D - 1) & (D - 1), (t + D - 1) * 32);
    waitv<(D - 1) * NL>();
    barrier_();
    compute(t & (D - 1));
    barrier_();
  }
  {
    int t = nst - D + 1;
    if constexpr (D >= 4) {
      waitv<2 * NL>(); barrier_(); compute(t & (D - 1)); barrier_(); ++t;
      waitv<1 * NL>(); barrier_(); compute(t & (D - 1)); barrier_(); ++t;
    }
    waitv<0>(); barrier_(); compute(t & (D - 1));
  }

  const int r0 = brow + wr * (BM / 2) + (lane >> 4) * 4;
  const int c0 = bcol + wc * (BN / 2) + (lane & 15);
#pragma unroll
  for (int m = 0; m < MF; ++m) {
#pragma unroll
    for (int j = 0; j < 4; ++j) {
      int row = r0 + m * 16 + j;
#pragma unroll
      for (int n = 0; n < NF; ++n) {
        int col = c0 + n * 16;
        float v = acc[m][n][j];
        int64_t idx = (int64_t)row * N + col;
        if (EPI == 0) {
          ((short*)Cp)[bz * sC + idx] = f2b(v);
        } else if (EPI == 2) {
          v = fmaxf(v, 0.0f);
          ((short*)Cp)[bz * sC + idx] = f2b(v * v);
        } else if (EPI == 3) {
          float r2 = v + e0[row] * e1[col] + e2[col];
          float xo = ((const float*)e3)[bz * sE + idx];
          ((float*)Cp)[bz * sC + idx] = xo * (1.0f + r2);
        } else if (EPI == 6) {
          ((short*)Cp)[bz * sC + idx] = f2b(bz == 2 ? sigm(v) : v);
        }
      }
    }
  }
}

// ---------------- launch ----------------
extern "C" void kernel_launch(void* const* d_in, const int* in_sizes, int n_in,
                              void* d_out, int out_size, void* d_ws,
                              size_t ws_size, hipStream_t stream) {
  const float* x   = (const float*)d_in[0];
  const float* rt  = (const float*)d_in[1];
  const float* td  = (const float*)d_in[2];
  const float* tf  = (const float*)d_in[3];
  const float* tmk = (const float*)d_in[4];
  const float* tmv = (const float*)d_in[5];
  const float* tmr = (const float*)d_in[6];
  const float* Wk  = (const float*)d_in[7];
  const float* Wv  = (const float*)d_in[8];
  const float* Wr  = (const float*)d_in[9];
  const float* Wo  = (const float*)d_in[10];
  const float* cmk = (const float*)d_in[11];
  const float* cmr = (const float*)d_in[12];
  const float* Wck = (const float*)d_in[13];
  const float* Wcv = (const float*)d_in[14];
  const float* Wcr = (const float*)d_in[15];
  const float* Wrm = (const float*)d_in[16];
  const float* brm = (const float*)d_in[17];
  const float* Wam = (const float*)d_in[18];
  const float* bam = (const float*)d_in[19];
  float* out = (float*)d_out;

  const size_t MB = 1ull << 20;
  uint8_t* W8 = (uint8_t*)d_ws;
  float* XC   = (float*)(W8);                        // 0-16 residual f32
  short* S1   = (short*)(W8 + 24 * MB);              // 24-32 xk / SRY / SRR
  short* S2   = (short*)(W8 + 32 * MB);              // 32-40 xv / xk2 / rtok,Mt
  short* S3   = (short*)(W8 + 40 * MB);              // 40-48 xr / xr2 / bWck
  short* bWcv = (short*)(W8 + 48 * MB);              // 48-56
  short* bWk  = (short*)(W8 + 56 * MB);              // 56-62
  short* bWo  = (short*)(W8 + 62 * MB);
  short* bWcr = (short*)(W8 + 64 * MB);
  short* bWrm = (short*)(W8 + 66 * MB);              // 0.5 MB
  short* bWam = (short*)(W8 + 66 * MB + 512 * 1024); // 0.5 MB
  short* KK   = (short*)(W8 + 67 * MB);              // 67-75
  short* VV   = (short*)(W8 + 75 * MB);              // 75-83
  short* RR   = (short*)(W8 + 83 * MB);              // 83-91
  float* Ca   = (float*)(W8 + 91 * MB);              // wkv temps 91-97
  float* Da   = (float*)(W8 + 92 * MB);
  float* Qa   = (float*)(W8 + 93 * MB);
  float* Aa   = (float*)(W8 + 94 * MB);
  float* Ba   = (float*)(W8 + 95 * MB);
  float* Pa   = (float*)(W8 + 96 * MB);
  short* SRY  = S1;
  short* xk2  = S2;
  short* xr2  = S3;
  short* SRR  = S1;
  short* bWck = S3;
  short* H16  = KK;                                  // 67-99 (32 MB)
  short* rtok = S2;                                  // 32-36 (tail)
  short* Mt   = (short*)(W8 + 36 * MB);              // 36-37 (tail)
  float* Sb   = (float*)(W8 + 99 * MB);              // 4 KB

  dim3 blk(256);
  dim3 blk512(512);

  // 0) ALL weight conversions + Wam row-sum in one launch
  cvt_all<<<5120, blk, 0, stream>>>(Wk, Wv, Wr, Wo, Wcr, Wcv, Wrm, Wam,
                                    bWk, bWk + 1048576, bWk + 2097152, bWo,
                                    bWcr, bWcv, bWrm, bWam, Sb);

  // 1) FUSED concat + ln1 + time-mix blends -> XC, S1, S2, S3
  ln_mix3<<<TB_ * TT_, blk, 0, stream>>>(x, rt, tmk, tmv, tmr, XC, S1, S2, S3);

  // 2) fused z=3 time-mix: KK/VV/RR (grid 768 = 3 blk/CU, D=2)
  gemm_bf16<128, 128, 6, 2, 3><<<dim3(8, 32, 3), blk, 0, stream>>>(
      S1, bWk, KK, 4096, 1024, 1024, 1024, 4194304, 1048576, 4194304,
      nullptr, nullptr, nullptr, nullptr, 0);
  // 3) wkv chunked scan -> SRY (=S1)
  wkv_p1<<<WKV_NCH * TB_ * 4, blk, 0, stream>>>(td, KK, VV, Ca, Da, Qa);
  wkv_p2<<<32, blk, 0, stream>>>(td, Ca, Da, Qa, Aa, Ba, Pa);
  wkv_p3<<<WKV_NCH * TB_ * 4, blk, 0, stream>>>(td, tf, KK, VV, RR, SRY,
                                                Aa, Ba, Pa);
  // 4) att: XC += lif(SRY*Wo^T)   (4-phase interleaved, 8 waves)
  gemm4p<4><<<dim3(8, 32), blk512, 0, stream>>>(
      SRY, bWo, XC, 4096, 1024, 1024, 1024, nullptr, nullptr, nullptr,
      nullptr);
  // 5) fused ln2+mix2 -> xk2(S2), xr2(S3)
  ln_mix2<<<TB_ * TT_, blk, 0, stream>>>(XC, cmk, cmr, xk2, xr2);
  // 6) SRR = sigm(xr2*Wcr^T) -> S1   (4-phase)
  gemm4p<1><<<dim3(8, 32), blk512, 0, stream>>>(
      xr2, bWcr, SRR, 4096, 1024, 1024, 1024, nullptr, nullptr, nullptr,
      nullptr);
  // 7) Wck -> bf16 into now-dead xr2 slot
  cvt_b<<<2048, blk, 0, stream>>>(Wck, bWck);
  // 8) H = relu^2(xk2*Wck^T) -> H16 (grid 1024 = 4 blk/CU, D=2)
  gemm_bf16<128, 128, 2, 2, 4><<<dim3(32, 32, 1), blk, 0, stream>>>(
      xk2, bWck, H16, 4096, 4096, 1024, 1024, 0, 0, 0,
      nullptr, nullptr, nullptr, nullptr, 0);
  // 9) XC += lif(SRR*(H*Wcv^T))   (4-phase, K=4096)
  gemm4p<5><<<dim3(8, 32), blk512, 0, stream>>>(
      H16, bWcv, XC, 4096, 1024, 4096, 4096, nullptr, nullptr, nullptr, SRR);
  // 10) tail
  cvt_rtok<<<1024, blk, 0, stream>>>(XC, rtok);
  gemm_bf16<64, 64, 0, 2, 2><<<dim3(4, 4, 8), blk, 0, stream>>>(
      bWrm, rtok, Mt, 256, 256, 1024, 1024, 0, (int64_t)256 * 1024,
      (int64_t)256 * 256, nullptr, nullptr, nullptr, nullptr, 0);
  gemm_bf16<64, 64, 3, 2, 2><<<dim3(16, 4, 8), blk, 0, stream>>>(
      Mt, bWam, out, 256, 1024, 256, 256, (int64_t)256 * 256, 0,
      (int64_t)256 * 1024, brm, Sb, bam, XC, (int64_t)512 * 1024);
}

// Round 17
// 304.576 us; speedup vs baseline: 1.1426x; 1.0788x over previous
//
#include <hip/hip_runtime.h>
#include <hip/hip_bf16.h>
#include <math.h>
#include <stdint.h>

// B=8, P1=256 -> T=512 concat rows, C=1024, H=4096
#define TB_ 8
#define TT_ 512
#define TC_ 1024
#define WKV_NCH 32
#define WKV_L 16

typedef __attribute__((ext_vector_type(8))) short bf16x8;
typedef __attribute__((ext_vector_type(4))) short s16x4;
typedef __attribute__((ext_vector_type(4))) float f32x4;

__device__ __forceinline__ float b2f(short u) {
  union { unsigned int i; float f; } x;
  x.i = ((unsigned int)(unsigned short)u) << 16;
  return x.f;
}
__device__ __forceinline__ short f2b(float f) {
  __hip_bfloat16 h = __float2bfloat16(f);  // RNE
  return __builtin_bit_cast(short, h);
}
__device__ __forceinline__ float sigm(float x) { return 1.0f / (1.0f + expf(-x)); }

__device__ __forceinline__ float lif4(float a) {
  float v = 0.0f, acc = 0.0f;
#pragma unroll
  for (int i = 0; i < 4; ++i) {
    v += (a - v) * 0.5f;
    float s = (v >= 1.0f) ? 1.0f : 0.0f;
    acc += s;
    v *= (1.0f - s);
  }
  return acc * 0.25f;
}

__device__ __forceinline__ void gload16(const void* g, void* l) {
  __builtin_amdgcn_global_load_lds(
      (__attribute__((address_space(1))) void*)(g),
      (__attribute__((address_space(3))) void*)(l), 16, 0, 0);
}

template <int N>
__device__ __forceinline__ void waitv() {
  if constexpr (N == 0)  asm volatile("s_waitcnt vmcnt(0)" ::: "memory");
  else if constexpr (N == 2)  asm volatile("s_waitcnt vmcnt(2)" ::: "memory");
  else if constexpr (N == 4)  asm volatile("s_waitcnt vmcnt(4)" ::: "memory");
  else if constexpr (N == 8)  asm volatile("s_waitcnt vmcnt(8)" ::: "memory");
  else if constexpr (N == 12) asm volatile("s_waitcnt vmcnt(12)" ::: "memory");
  else static_assert(N == 0, "unsupported vmcnt");
}
__device__ __forceinline__ void barrier_() {
  asm volatile("s_barrier" ::: "memory");
}

// ---------------- elementwise kernels ----------------

// FUSED concat + ln1 + time-mix blends (one 256-thr block per row).
__global__ __launch_bounds__(256) void ln_mix3(
    const float* __restrict__ x, const float* __restrict__ rt,
    const float* __restrict__ tmk, const float* __restrict__ tmv,
    const float* __restrict__ tmr, float* __restrict__ xc,
    short* __restrict__ xk, short* __restrict__ xv, short* __restrict__ xr) {
  __shared__ float red[256];
  int row = blockIdx.x;
  int t = row & 511, b = row >> 9;
  int tid = threadIdx.x;
  const float* src = (t < 256) ? x + (int64_t)(b * 256 + t) * TC_
                               : rt + (int64_t)(t - 256) * TC_;
  float4 v = ((const float4*)src)[tid];
  ((float4*)(xc + (int64_t)row * TC_))[tid] = v;
  red[tid] = v.x + v.y + v.z + v.w;
  __syncthreads();
  for (int off = 128; off > 0; off >>= 1) {
    if (tid < off) red[tid] += red[tid + off];
    __syncthreads();
  }
  float mean = red[0] * (1.0f / 1024.0f);
  __syncthreads();
  float dx = v.x - mean, dy = v.y - mean, dz = v.z - mean, dw = v.w - mean;
  red[tid] = dx * dx + dy * dy + dz * dz + dw * dw;
  __syncthreads();
  for (int off = 128; off > 0; off >>= 1) {
    if (tid < off) red[tid] += red[tid + off];
    __syncthreads();
  }
  float rs = 1.0f / sqrtf(red[0] * (1.0f / 1024.0f) + 1e-6f);
  float c0 = dx * rs, c1 = dy * rs, c2 = dz * rs, c3 = dw * rs;
  float p0 = 0.f, p1 = 0.f, p2 = 0.f, p3 = 0.f;
  if (t > 0) {  // block-uniform
    int tp = t - 1;
    const float* srcp = (tp < 256) ? x + (int64_t)(b * 256 + tp) * TC_
                                   : rt + (int64_t)(tp - 256) * TC_;
    __syncthreads();
    float4 w4 = ((const float4*)srcp)[tid];
    red[tid] = w4.x + w4.y + w4.z + w4.w;
    __syncthreads();
    for (int off = 128; off > 0; off >>= 1) {
      if (tid < off) red[tid] += red[tid + off];
      __syncthreads();
    }
    float meanp = red[0] * (1.0f / 1024.0f);
    __syncthreads();
    float ex = w4.x - meanp, ey = w4.y - meanp, ez = w4.z - meanp,
          ew = w4.w - meanp;
    red[tid] = ex * ex + ey * ey + ez * ez + ew * ew;
    __syncthreads();
    for (int off = 128; off > 0; off >>= 1) {
      if (tid < off) red[tid] += red[tid + off];
      __syncthreads();
    }
    float rsp = 1.0f / sqrtf(red[0] * (1.0f / 1024.0f) + 1e-6f);
    p0 = ex * rsp; p1 = ey * rsp; p2 = ez * rsp; p3 = ew * rsp;
  }
  int c = tid * 4;
  int64_t o = (int64_t)row * TC_ + c;
  float m0, m1, m2, m3;
  s16x4 ov;
  m0 = tmk[c]; m1 = tmk[c + 1]; m2 = tmk[c + 2]; m3 = tmk[c + 3];
  ov.x = f2b(c0 * m0 + p0 * (1.0f - m0));
  ov.y = f2b(c1 * m1 + p1 * (1.0f - m1));
  ov.z = f2b(c2 * m2 + p2 * (1.0f - m2));
  ov.w = f2b(c3 * m3 + p3 * (1.0f - m3));
  *(s16x4*)(xk + o) = ov;
  m0 = tmv[c]; m1 = tmv[c + 1]; m2 = tmv[c + 2]; m3 = tmv[c + 3];
  ov.x = f2b(c0 * m0 + p0 * (1.0f - m0));
  ov.y = f2b(c1 * m1 + p1 * (1.0f - m1));
  ov.z = f2b(c2 * m2 + p2 * (1.0f - m2));
  ov.w = f2b(c3 * m3 + p3 * (1.0f - m3));
  *(s16x4*)(xv + o) = ov;
  m0 = tmr[c]; m1 = tmr[c + 1]; m2 = tmr[c + 2]; m3 = tmr[c + 3];
  ov.x = f2b(c0 * m0 + p0 * (1.0f - m0));
  ov.y = f2b(c1 * m1 + p1 * (1.0f - m1));
  ov.z = f2b(c2 * m2 + p2 * (1.0f - m2));
  ov.w = f2b(c3 * m3 + p3 * (1.0f - m3));
  *(s16x4*)(xr + o) = ov;
}

// fused ln2 + channel-mix blend (same recompute pattern).
__global__ __launch_bounds__(256) void ln_mix2(const float* __restrict__ xc,
                                               const float* __restrict__ cmk,
                                               const float* __restrict__ cmr,
                                               short* __restrict__ xk,
                                               short* __restrict__ xr) {
  __shared__ float red[256];
  int row = blockIdx.x;
  int t = row & 511;
  int tid = threadIdx.x;
  float4 v = ((const float4*)(xc + (int64_t)row * TC_))[tid];
  red[tid] = v.x + v.y + v.z + v.w;
  __syncthreads();
  for (int off = 128; off > 0; off >>= 1) {
    if (tid < off) red[tid] += red[tid + off];
    __syncthreads();
  }
  float mean = red[0] * (1.0f / 1024.0f);
  __syncthreads();
  float dx = v.x - mean, dy = v.y - mean, dz = v.z - mean, dw = v.w - mean;
  red[tid] = dx * dx + dy * dy + dz * dz + dw * dw;
  __syncthreads();
  for (int off = 128; off > 0; off >>= 1) {
    if (tid < off) red[tid] += red[tid + off];
    __syncthreads();
  }
  float rs = 1.0f / sqrtf(red[0] * (1.0f / 1024.0f) + 1e-6f);
  float c0 = dx * rs, c1 = dy * rs, c2 = dz * rs, c3 = dw * rs;
  float p0 = 0.f, p1 = 0.f, p2 = 0.f, p3 = 0.f;
  if (t > 0) {
    __syncthreads();
    float4 w4 = ((const float4*)(xc + (int64_t)(row - 1) * TC_))[tid];
    red[tid] = w4.x + w4.y + w4.z + w4.w;
    __syncthreads();
    for (int off = 128; off > 0; off >>= 1) {
      if (tid < off) red[tid] += red[tid + off];
      __syncthreads();
    }
    float meanp = red[0] * (1.0f / 1024.0f);
    __syncthreads();
    float ex = w4.x - meanp, ey = w4.y - meanp, ez = w4.z - meanp,
          ew = w4.w - meanp;
    red[tid] = ex * ex + ey * ey + ez * ez + ew * ew;
    __syncthreads();
    for (int off = 128; off > 0; off >>= 1) {
      if (tid < off) red[tid] += red[tid + off];
      __syncthreads();
    }
    float rsp = 1.0f / sqrtf(red[0] * (1.0f / 1024.0f) + 1e-6f);
    p0 = ex * rsp; p1 = ey * rsp; p2 = ez * rsp; p3 = ew * rsp;
  }
  int c = tid * 4;
  float k0 = cmk[c], k1 = cmk[c + 1], k2 = cmk[c + 2], k3 = cmk[c + 3];
  float r0 = cmr[c], r1 = cmr[c + 1], r2 = cmr[c + 2], r3 = cmr[c + 3];
  s16x4 ok, orr;
  ok.x = f2b(c0 * k0 + p0 * (1.0f - k0));
  ok.y = f2b(c1 * k1 + p1 * (1.0f - k1));
  ok.z = f2b(c2 * k2 + p2 * (1.0f - k2));
  ok.w = f2b(c3 * k3 + p3 * (1.0f - k3));
  orr.x = f2b(c0 * r0 + p0 * (1.0f - r0));
  orr.y = f2b(c1 * r1 + p1 * (1.0f - r1));
  orr.z = f2b(c2 * r2 + p2 * (1.0f - r2));
  orr.w = f2b(c3 * r3 + p3 * (1.0f - r3));
  *(s16x4*)(xk + (int64_t)row * TC_ + c) = ok;
  *(s16x4*)(xr + (int64_t)row * TC_ + c) = orr;
}

// f32 -> bf16, 8 elems/thread
__global__ __launch_bounds__(256) void cvt_b(const float* __restrict__ src,
                                             short* __restrict__ dst) {
  int64_t i = (int64_t)(blockIdx.x * 256 + threadIdx.x) * 8;
  float4 a = *(const float4*)(src + i);
  float4 b = *(const float4*)(src + i + 4);
  bf16x8 o;
  o[0] = f2b(a.x); o[1] = f2b(a.y); o[2] = f2b(a.z); o[3] = f2b(a.w);
  o[4] = f2b(b.x); o[5] = f2b(b.y); o[6] = f2b(b.z); o[7] = f2b(b.w);
  *(bf16x8*)(dst + i) = o;
}

// rtok rows (per b: rows 256..511 of XC) f32 -> bf16 contiguous (B,256,C)
__global__ __launch_bounds__(256) void cvt_rtok(const float* __restrict__ xc,
                                                short* __restrict__ dst) {
  int i = blockIdx.x * 256 + threadIdx.x;  // short8 idx
  int b = i >> 15;
  int rem = i & 32767;
  const float* s = xc + (int64_t)b * 524288 + 262144 + (int64_t)rem * 8;
  float4 a = *(const float4*)s;
  float4 c = *(const float4*)(s + 4);
  bf16x8 o;
  o[0] = f2b(a.x); o[1] = f2b(a.y); o[2] = f2b(a.z); o[3] = f2b(a.w);
  o[4] = f2b(c.x); o[5] = f2b(c.y); o[6] = f2b(c.z); o[7] = f2b(c.w);
  *(bf16x8*)(dst + (int64_t)i * 8) = o;
}

// ONE launch: convert 8 weight arrays f32->bf16 + fused Wam row-sum.
__global__ __launch_bounds__(256) void cvt_all(
    const float* __restrict__ Wk, const float* __restrict__ Wv,
    const float* __restrict__ Wr, const float* __restrict__ Wo,
    const float* __restrict__ Wcr, const float* __restrict__ Wcv,
    const float* __restrict__ Wrm, const float* __restrict__ Wam,
    short* __restrict__ bWk, short* __restrict__ bWv, short* __restrict__ bWr,
    short* __restrict__ bWo, short* __restrict__ bWcr, short* __restrict__ bWcv,
    short* __restrict__ bWrm, short* __restrict__ bWam,
    float* __restrict__ S) {
  int bid = blockIdx.x;
  if (bid >= 4864) {
    int row = (bid - 4864) * 4 + (threadIdx.x >> 6);
    int lane = threadIdx.x & 63;
    float4 v = ((const float4*)(Wam + (int64_t)row * 256))[lane];
    float s = v.x + v.y + v.z + v.w;
    for (int off = 32; off > 0; off >>= 1) s += __shfl_down(s, off);
    if (lane == 0) S[row] = s;
    return;
  }
  const float* src; short* dst; int base;
  if (bid < 512)       { src = Wk;  dst = bWk;  base = bid; }
  else if (bid < 1024) { src = Wv;  dst = bWv;  base = bid - 512; }
  else if (bid < 1536) { src = Wr;  dst = bWr;  base = bid - 1024; }
  else if (bid < 2048) { src = Wo;  dst = bWo;  base = bid - 1536; }
  else if (bid < 2560) { src = Wcr; dst = bWcr; base = bid - 2048; }
  else if (bid < 4608) { src = Wcv; dst = bWcv; base = bid - 2560; }
  else if (bid < 4736) { src = Wrm; dst = bWrm; base = bid - 4608; }
  else                 { src = Wam; dst = bWam; base = bid - 4736; }
  int64_t i = ((int64_t)base * 256 + threadIdx.x) * 8;
  float4 a = *(const float4*)(src + i);
  float4 b = *(const float4*)(src + i + 4);
  bf16x8 o;
  o[0] = f2b(a.x); o[1] = f2b(a.y); o[2] = f2b(a.z); o[3] = f2b(a.w);
  o[4] = f2b(b.x); o[5] = f2b(b.y); o[6] = f2b(b.z); o[7] = f2b(b.w);
  *(bf16x8*)(dst + i) = o;
}

// ---------------- wkv chunked parallel scan ----------------
__global__ __launch_bounds__(256) void wkv_p1(const float* __restrict__ td,
                                              const short* __restrict__ K,
                                              const short* __restrict__ V,
                                              float* __restrict__ Ca,
                                              float* __restrict__ Da,
                                              float* __restrict__ Qa) {
  int bx = blockIdx.x;
  int ch = bx >> 5;
  int b = (bx >> 2) & 7;
  int c = (bx & 3) * 256 + threadIdx.x;
  float w = -expf(td[c]);
  float aa = 0.0f, bb = 0.0f, pp = -1e38f;
  int64_t base = ((int64_t)b * TT_ + ch * WKV_L) * TC_ + c;
#pragma unroll
  for (int t = 0; t < WKV_L; ++t) {
    int64_t o = base + (int64_t)t * TC_;
    float kt = b2f(K[o]), vt = b2f(V[o]);
    float ww2 = pp + w;
    float p2 = fmaxf(ww2, kt);
    float e1 = expf(ww2 - p2);
    float e2 = expf(kt - p2);
    aa = e1 * aa + e2 * vt;
    bb = e1 * bb + e2;
    pp = p2;
  }
  int idx = ch * 8192 + b * 1024 + c;
  Ca[idx] = aa; Da[idx] = bb; Qa[idx] = pp;
}

__global__ __launch_bounds__(256) void wkv_p2(const float* __restrict__ td,
                                              const float* __restrict__ Ca,
                                              const float* __restrict__ Da,
                                              const float* __restrict__ Qa,
                                              float* __restrict__ Aa,
                                              float* __restrict__ Ba,
                                              float* __restrict__ Pa) {
  int i = blockIdx.x * 256 + threadIdx.x;
  int c = i & (TC_ - 1);
  float wL = -expf(td[c]) * (float)WKV_L;
  float aa = 0.0f, bb = 0.0f, pp = -1e38f;
#pragma unroll 4
  for (int ch = 0; ch < WKV_NCH; ++ch) {
    int idx = ch * 8192 + i;
    Aa[idx] = aa; Ba[idx] = bb; Pa[idx] = pp;
    float ppw = pp + wL;
    float q = Qa[idx];
    float p2 = fmaxf(ppw, q);
    float ea = expf(ppw - p2);
    float eb = expf(q - p2);
    aa = aa * ea + Ca[idx] * eb;
    bb = bb * ea + Da[idx] * eb;
    pp = p2;
  }
}

__global__ __launch_bounds__(256) void wkv_p3(const float* __restrict__ td,
                                              const float* __restrict__ tf,
                                              const short* __restrict__ K,
                                              const short* __restrict__ V,
                                              const short* __restrict__ SR,
                                              short* __restrict__ SRY,
                                              const float* __restrict__ Aa,
                                              const float* __restrict__ Ba,
                                              const float* __restrict__ Pa) {
  int bx = blockIdx.x;
  int ch = bx >> 5;
  int b = (bx >> 2) & 7;
  int c = (bx & 3) * 256 + threadIdx.x;
  float w = -expf(td[c]);
  float u = tf[c];
  int idx = ch * 8192 + b * 1024 + c;
  float aa = Aa[idx], bb = Ba[idx], pp = Pa[idx];
  int64_t base = ((int64_t)b * TT_ + ch * WKV_L) * TC_ + c;
#pragma unroll
  for (int t = 0; t < WKV_L; ++t) {
    int64_t o = base + (int64_t)t * TC_;
    float kt = b2f(K[o]), vt = b2f(V[o]);
    float ww = u + kt;
    float p = fmaxf(pp, ww);
    float E1 = expf(pp - p);
    float E2 = expf(ww - p);
    float y = (E1 * aa + E2 * vt) / (E1 * bb + E2);
    SRY[o] = f2b(y * b2f(SR[o]));
    float ww2 = pp + w;
    float p2 = fmaxf(ww2, kt);
    float e1 = expf(ww2 - p2);
    float e2 = expf(kt - p2);
    aa = e1 * aa + e2 * vt;
    bb = e1 * bb + e2;
    pp = p2;
  }
}

// ---------------- 4-phase interleaved MFMA GEMM, 128x128 (N=1024) -------
// (R16-proven.) 8 waves, BK=64, dbuf LDS, counted vmcnt at P1/P3.
// EPI: 1 sigmoid bf16; 4 XC += lif4(acc); 5 XC += lif4(acc * srr(e3)).
template <int EPI>
__global__ __launch_bounds__(512, 1) void gemm4p(
    const short* __restrict__ A, const short* __restrict__ B,
    void* __restrict__ Cp, int M, int N, int K, int Kst,
    const float* __restrict__ e0, const float* __restrict__ e1,
    const float* __restrict__ e2, const void* __restrict__ e3) {
  __shared__ short lds[2 * 32768];
  const int tid = threadIdx.x;

  const unsigned gx = gridDim.x, gy = gridDim.y;
  const unsigned nwg = gx * gy;
  const unsigned lin = blockIdx.x + gx * blockIdx.y;
  const unsigned cs = nwg >> 3;
  const unsigned nl = (lin & 7) * cs + (lin >> 3);
  const unsigned bxs = nl % gx;
  const unsigned bys = nl / gx;

  const int brow = bys * 128;
  const int bcol = bxs * 128;

  const int srow = ((tid >> 6) << 4) + (tid & 15);
  const int skc = ((tid >> 4) & 3) * 8;
  const short* gA = A + (int64_t)(brow + srow) * Kst + skc;
  const short* gB = B + (int64_t)(bcol + srow) * Kst + skc;

  const int lane = tid & 63, wid = tid >> 6;
  const int wr = wid >> 2, wc = wid & 3;

  f32x4 acc[4][2] = {};

#define RD_A(rb, kh, m) \
  (*(const bf16x8*)(lds + (rb) * 32768 + (kh) * 8192 + (wr * 4 + (m)) * 512 + lane * 8))
#define RD_B(rb, kh, n) \
  (*(const bf16x8*)(lds + (rb) * 32768 + 16384 + (kh) * 8192 + (wc * 2 + (n)) * 512 + lane * 8))
#define ST_A(sb, kh, kt) \
  gload16(gA + (kt) * 64 + (kh) * 32, lds + (sb) * 32768 + (kh) * 8192 + tid * 8)
#define ST_B(sb, kh, kt) \
  gload16(gB + (kt) * 64 + (kh) * 32, lds + (sb) * 32768 + 16384 + (kh) * 8192 + tid * 8)
#define MM(am, bn, i, j) \
  acc[i][j] = __builtin_amdgcn_mfma_f32_16x16x32_bf16(am, bn, acc[i][j], 0, 0, 0)

  const int nt = K / 64;
  ST_A(0, 0, 0); ST_B(0, 0, 0); ST_A(0, 1, 0); ST_B(0, 1, 0);
  waitv<2>();
  barrier_();

  for (int t = 0; t < nt - 1; ++t) {
    const int rb = t & 1, sb = rb ^ 1, kn = t + 1;
    {
      bf16x8 a0 = RD_A(rb, 0, 0), a1 = RD_A(rb, 0, 1);
      bf16x8 b0 = RD_B(rb, 0, 0), b1 = RD_B(rb, 0, 1);
      ST_A(sb, 0, kn);
      MM(a0, b0, 0, 0); MM(a0, b1, 0, 1); MM(a1, b0, 1, 0); MM(a1, b1, 1, 1);
      barrier_();
      bf16x8 a2 = RD_A(rb, 0, 2), a3 = RD_A(rb, 0, 3);
      ST_B(sb, 0, kn);
      MM(a2, b0, 2, 0); MM(a2, b1, 2, 1); MM(a3, b0, 3, 0); MM(a3, b1, 3, 1);
      waitv<2>();
      barrier_();
    }
    {
      bf16x8 a0 = RD_A(rb, 1, 0), a1 = RD_A(rb, 1, 1);
      bf16x8 b0 = RD_B(rb, 1, 0), b1 = RD_B(rb, 1, 1);
      ST_A(sb, 1, kn);
      MM(a0, b0, 0, 0); MM(a0, b1, 0, 1); MM(a1, b0, 1, 0); MM(a1, b1, 1, 1);
      barrier_();
      bf16x8 a2 = RD_A(rb, 1, 2), a3 = RD_A(rb, 1, 3);
      ST_B(sb, 1, kn);
      MM(a2, b0, 2, 0); MM(a2, b1, 2, 1); MM(a3, b0, 3, 0); MM(a3, b1, 3, 1);
      waitv<2>();
      barrier_();
    }
  }
  {
    waitv<0>();
    barrier_();
    const int rb = (nt - 1) & 1;
#pragma unroll
    for (int kh = 0; kh < 2; ++kh) {
      bf16x8 a0 = RD_A(rb, kh, 0), a1 = RD_A(rb, kh, 1);
      bf16x8 a2 = RD_A(rb, kh, 2), a3 = RD_A(rb, kh, 3);
      bf16x8 b0 = RD_B(rb, kh, 0), b1 = RD_B(rb, kh, 1);
      MM(a0, b0, 0, 0); MM(a0, b1, 0, 1); MM(a1, b0, 1, 0); MM(a1, b1, 1, 1);
      MM(a2, b0, 2, 0); MM(a2, b1, 2, 1); MM(a3, b0, 3, 0); MM(a3, b1, 3, 1);
    }
  }
#undef RD_A
#undef RD_B
#undef ST_A
#undef ST_B
#undef MM

  const int r0 = brow + wr * 64 + (lane >> 4) * 4;
  const int c0 = bcol + wc * 32 + (lane & 15);
#pragma unroll
  for (int m = 0; m < 4; ++m) {
#pragma unroll
    for (int j = 0; j < 4; ++j) {
      int row = r0 + m * 16 + j;
#pragma unroll
      for (int n = 0; n < 2; ++n) {
        int col = c0 + n * 16;
        float v = acc[m][n][j];
        int64_t idx = (int64_t)row * N + col;
        if (EPI == 1) {
          ((short*)Cp)[idx] = f2b(sigm(v));
        } else if (EPI == 4) {
          float* XC = (float*)Cp;
          XC[idx] = XC[idx] + lif4(v);
        } else if (EPI == 5) {
          float* XC = (float*)Cp;
          float srr = b2f(((const short*)e3)[idx]);
          XC[idx] = XC[idx] + lif4(v * srr);
        }
      }
    }
  }
}

// ---------------- 4-phase interleaved MFMA GEMM, 256x256 (H shape) ------
// Scaled gemm4p: 256^2 tile, 8 waves (2Mx4N, each owns 128x64), BK=64,
// double-buffered 128 KB LDS in MFMA lane order. 16 MFMA per phase vs
// 4-8 ds_read_b128 + 2 stage -- 4x the MFMA density of gemm4p's phases
// (which were LDS-issue paced at MfmaUtil 18%). Same wait discipline,
// re-derived for 2-load stages: per iter issue order Ah0,Bh0,Ah1,Bh1
// (2 loads each); waitv<4> at P1 end retires tile t's h1 (read in P2/P3);
// waitv<4> at P3 end retires tile t+1's h0 (read at next P0). Each wait
// precedes a barrier (cross-wave publish). K-accumulation order unchanged
// vs 2-barrier kernel -> bit-identical results.
// EPI: 2 relu^2 -> bf16.
template <int EPI>
__global__ __launch_bounds__(512, 1) void gemm256(
    const short* __restrict__ A, const short* __restrict__ B,
    void* __restrict__ Cp, int M, int N, int K, int Kst) {
  __shared__ short lds[2 * 32768];  // 2 x 64KB: [Ah0 16K][Ah1][Bh0][Bh1]
  const int tid = threadIdx.x;

  const unsigned gx = gridDim.x, gy = gridDim.y;
  const unsigned nwg = gx * gy;             // 256 -> %8==0
  const unsigned lin = blockIdx.x + gx * blockIdx.y;
  const unsigned cs = nwg >> 3;
  const unsigned nl = (lin & 7) * cs + (lin >> 3);
  const unsigned bxs = nl % gx;
  const unsigned bys = nl / gx;

  const int brow = bys * 256;
  const int bcol = bxs * 256;

  // staging: thread stages 2 chunks per (matrix, half): p = c*512+tid,
  // subtile u=p>>6 (16 rows), slot s=p&63 -> row u*16+(s&15), k8=s>>4.
  const short* gA[2];
  const short* gB[2];
  int loff[2];
#pragma unroll
  for (int c = 0; c < 2; ++c) {
    int p = c * 512 + tid;
    int u = p >> 6, s = p & 63;
    gA[c] = A + (int64_t)(brow + u * 16 + (s & 15)) * Kst + (s >> 4) * 8;
    gB[c] = B + (int64_t)(bcol + u * 16 + (s & 15)) * Kst + (s >> 4) * 8;
    loff[c] = p * 8;
  }

  const int lane = tid & 63, wid = tid >> 6;
  const int wr = wid >> 2, wc = wid & 3;  // wave owns rows wr*128, cols wc*64

  f32x4 acc[8][4] = {};

#define RD_A(rb, kh, m) \
  (*(const bf16x8*)(lds + (rb) * 32768 + (kh) * 8192 + (wr * 8 + (m)) * 512 + lane * 8))
#define RD_B(rb, kh, n) \
  (*(const bf16x8*)(lds + (rb) * 32768 + 16384 + (kh) * 8192 + (wc * 4 + (n)) * 512 + lane * 8))
#define ST_A(sb, kh, kt)                                                     \
  {                                                                          \
    gload16(gA[0] + (kt) * 64 + (kh) * 32,                                   \
            lds + (sb) * 32768 + (kh) * 8192 + loff[0]);                     \
    gload16(gA[1] + (kt) * 64 + (kh) * 32,                                   \
            lds + (sb) * 32768 + (kh) * 8192 + loff[1]);                     \
  }
#define ST_B(sb, kh, kt)                                                     \
  {                                                                          \
    gload16(gB[0] + (kt) * 64 + (kh) * 32,                                   \
            lds + (sb) * 32768 + 16384 + (kh) * 8192 + loff[0]);             \
    gload16(gB[1] + (kt) * 64 + (kh) * 32,                                   \
            lds + (sb) * 32768 + 16384 + (kh) * 8192 + loff[1]);             \
  }
#define MM(am, bn, i, j) \
  acc[i][j] = __builtin_amdgcn_mfma_f32_16x16x32_bf16(am, bn, acc[i][j], 0, 0, 0)

  const int nt = K / 64;
  // prologue: stage tile 0 (Ah0, Bh0, Ah1, Bh1)
  ST_A(0, 0, 0); ST_B(0, 0, 0); ST_A(0, 1, 0); ST_B(0, 1, 0);
  waitv<4>();  // Ah0+Bh0 resident
  barrier_();

  for (int t = 0; t < nt - 1; ++t) {
    const int rb = t & 1, sb = rb ^ 1, kn = t + 1;
    bf16x8 b0, b1, b2, b3;
    // P0: kh=0, m0-3
    {
      bf16x8 a0 = RD_A(rb, 0, 0), a1 = RD_A(rb, 0, 1);
      bf16x8 a2 = RD_A(rb, 0, 2), a3 = RD_A(rb, 0, 3);
      b0 = RD_B(rb, 0, 0); b1 = RD_B(rb, 0, 1);
      b2 = RD_B(rb, 0, 2); b3 = RD_B(rb, 0, 3);
      ST_A(sb, 0, kn);
      MM(a0, b0, 0, 0); MM(a0, b1, 0, 1); MM(a0, b2, 0, 2); MM(a0, b3, 0, 3);
      MM(a1, b0, 1, 0); MM(a1, b1, 1, 1); MM(a1, b2, 1, 2); MM(a1, b3, 1, 3);
      MM(a2, b0, 2, 0); MM(a2, b1, 2, 1); MM(a2, b2, 2, 2); MM(a2, b3, 2, 3);
      MM(a3, b0, 3, 0); MM(a3, b1, 3, 1); MM(a3, b2, 3, 2); MM(a3, b3, 3, 3);
      barrier_();
    }
    // P1: kh=0, m4-7 (reuse b0-3)
    {
      bf16x8 a4 = RD_A(rb, 0, 4), a5 = RD_A(rb, 0, 5);
      bf16x8 a6 = RD_A(rb, 0, 6), a7 = RD_A(rb, 0, 7);
      ST_B(sb, 0, kn);
      MM(a4, b0, 4, 0); MM(a4, b1, 4, 1); MM(a4, b2, 4, 2); MM(a4, b3, 4, 3);
      MM(a5, b0, 5, 0); MM(a5, b1, 5, 1); MM(a5, b2, 5, 2); MM(a5, b3, 5, 3);
      MM(a6, b0, 6, 0); MM(a6, b1, 6, 1); MM(a6, b2, 6, 2); MM(a6, b3, 6, 3);
      MM(a7, b0, 7, 0); MM(a7, b1, 7, 1); MM(a7, b2, 7, 2); MM(a7, b3, 7, 3);
      waitv<4>();  // retire tile t's Ah1+Bh1 (read next phases)
      barrier_();
    }
    // P2: kh=1, m0-3
    {
      bf16x8 a0 = RD_A(rb, 1, 0), a1 = RD_A(rb, 1, 1);
      bf16x8 a2 = RD_A(rb, 1, 2), a3 = RD_A(rb, 1, 3);
      b0 = RD_B(rb, 1, 0); b1 = RD_B(rb, 1, 1);
      b2 = RD_B(rb, 1, 2); b3 = RD_B(rb, 1, 3);
      ST_A(sb, 1, kn);
      MM(a0, b0, 0, 0); MM(a0, b1, 0, 1); MM(a0, b2, 0, 2); MM(a0, b3, 0, 3);
      MM(a1, b0, 1, 0); MM(a1, b1, 1, 1); MM(a1, b2, 1, 2); MM(a1, b3, 1, 3);
      MM(a2, b0, 2, 0); MM(a2, b1, 2, 1); MM(a2, b2, 2, 2); MM(a2, b3, 2, 3);
      MM(a3, b0, 3, 0); MM(a3, b1, 3, 1); MM(a3, b2, 3, 2); MM(a3, b3, 3, 3);
      barrier_();
    }
    // P3: kh=1, m4-7
    {
      bf16x8 a4 = RD_A(rb, 1, 4), a5 = RD_A(rb, 1, 5);
      bf16x8 a6 = RD_A(rb, 1, 6), a7 = RD_A(rb, 1, 7);
      ST_B(sb, 1, kn);
      MM(a4, b0, 4, 0); MM(a4, b1, 4, 1); MM(a4, b2, 4, 2); MM(a4, b3, 4, 3);
      MM(a5, b0, 5, 0); MM(a5, b1, 5, 1); MM(a5, b2, 5, 2); MM(a5, b3, 5, 3);
      MM(a6, b0, 6, 0); MM(a6, b1, 6, 1); MM(a6, b2, 6, 2); MM(a6, b3, 6, 3);
      MM(a7, b0, 7, 0); MM(a7, b1, 7, 1); MM(a7, b2, 7, 2); MM(a7, b3, 7, 3);
      waitv<4>();  // retire tile t+1's Ah0+Bh0 (read at next P0)
      barrier_();
    }
  }
  // final tile
  {
    waitv<0>();
    barrier_();
    const int rb = (nt - 1) & 1;
#pragma unroll
    for (int kh = 0; kh < 2; ++kh) {
      bf16x8 b0 = RD_B(rb, kh, 0), b1 = RD_B(rb, kh, 1);
      bf16x8 b2 = RD_B(rb, kh, 2), b3 = RD_B(rb, kh, 3);
#pragma unroll
      for (int m = 0; m < 8; ++m) {
        bf16x8 am = RD_A(rb, kh, m);
        MM(am, b0, m, 0); MM(am, b1, m, 1);
        MM(am, b2, m, 2); MM(am, b3, m, 3);
      }
    }
  }
#undef RD_A
#undef RD_B
#undef ST_A
#undef ST_B
#undef MM

  const int r0 = brow + wr * 128 + (lane >> 4) * 4;
  const int c0 = bcol + wc * 64 + (lane & 15);
#pragma unroll
  for (int m = 0; m < 8; ++m) {
#pragma unroll
    for (int j = 0; j < 4; ++j) {
      int row = r0 + m * 16 + j;
#pragma unroll
      for (int n = 0; n < 4; ++n) {
        int col = c0 + n * 16;
        float v = acc[m][n][j];
        int64_t idx = (int64_t)row * N + col;
        if (EPI == 2) {
          v = fmaxf(v, 0.0f);
          ((short*)Cp)[idx] = f2b(v * v);
        }
      }
    }
  }
}

// ---------------- LDS MFMA GEMM (2-barrier path: tmix, tails) -----------
template <int BM, int BN, int EPI, int D, int MINW>
__global__ __launch_bounds__(256, MINW) void gemm_bf16(
    const short* __restrict__ A, const short* __restrict__ B,
    void* __restrict__ Cp, int M, int N, int K, int Kst,
    int64_t sA, int64_t sB, int64_t sC,
    const float* __restrict__ e0, const float* __restrict__ e1,
    const float* __restrict__ e2, const void* __restrict__ e3, int64_t sE) {
  constexpr int MF = BM / 32;
  constexpr int NF = BN / 32;
  constexpr int ASLOT = BM / 64;
  constexpr int BSLOT = BN / 64;
  constexpr int NL = ASLOT + BSLOT;
  constexpr int SBUF = (BM + BN) * 32;
  __shared__ short lds[D * SBUF];
  const int tid = threadIdx.x;

  const unsigned gx = gridDim.x, gy = gridDim.y;
  const unsigned nwg = gx * gy * gridDim.z;
  const unsigned lin = blockIdx.x + gx * (blockIdx.y + gy * blockIdx.z);
  const unsigned cs = nwg >> 3;
  const unsigned nl = (lin & 7) * cs + (lin >> 3);
  const unsigned bxs = nl % gx;
  const unsigned tmp = nl / gx;
  const unsigned bys = tmp % gy;
  const unsigned bz = tmp / gy;

  const int brow = bys * BM;
  const int bcol = bxs * BN;
  const short* Ab = A + bz * sA;
  const short* Bb = B + bz * sB;

  const int srow = ((tid >> 6) << 4) + (tid & 15);
  const int skc = ((tid >> 4) & 3) * 8;
  const short* gA[ASLOT];
  const short* gB[BSLOT];
#pragma unroll
  for (int s = 0; s < ASLOT; ++s)
    gA[s] = Ab + (int64_t)(brow + s * 64 + srow) * Kst + skc;
#pragma unroll
  for (int s = 0; s < BSLOT; ++s)
    gB[s] = Bb + (int64_t)(bcol + s * 64 + srow) * Kst + skc;

  const int lane = tid & 63, wid = tid >> 6;
  const int wr = wid >> 1, wc = wid & 1;

  f32x4 acc[MF][NF] = {};

  auto stage = [&](int buf, int k0) {
    short* d = lds + buf * SBUF;
#pragma unroll
    for (int s = 0; s < ASLOT; ++s)
      gload16(gA[s] + k0, d + s * 2048 + tid * 8);
#pragma unroll
    for (int s = 0; s < BSLOT; ++s)
      gload16(gB[s] + k0, d + BM * 32 + s * 2048 + tid * 8);
  };
  auto compute = [&](int buf) {
    const short* base = lds + buf * SBUF;
    bf16x8 af[MF], bfv[NF];
#pragma unroll
    for (int m = 0; m < MF; ++m)
      af[m] = *(const bf16x8*)(base + (wr * MF + m) * 512 + lane * 8);
#pragma unroll
    for (int n = 0; n < NF; ++n)
      bfv[n] = *(const bf16x8*)(base + BM * 32 + (wc * NF + n) * 512 + lane * 8);
#pragma unroll
    for (int m = 0; m < MF; ++m)
#pragma unroll
      for (int n = 0; n < NF; ++n)
        acc[m][n] = __builtin_amdgcn_mfma_f32_16x16x32_bf16(af[m], bfv[n],
                                                            acc[m][n], 0, 0, 0);
  };

  const int nst = K / 32;
#pragma unroll
  for (int d = 0; d < D - 1; ++d) stage(d, d * 32);
  for (int t = 0; t <= nst - D; ++t) {
    stage((t + D - 1) & (D - 1), (t + D - 1) * 32);
    waitv<(D - 1) * NL>();
    barrier_();
    compute(t & (D - 1));
    barrier_();
  }
  {
    int t = nst - D + 1;
    if constexpr (D >= 4) {
      waitv<2 * NL>(); barrier_(); compute(t & (D - 1)); barrier_(); ++t;
      waitv<1 * NL>(); barrier_(); compute(t & (D - 1)); barrier_(); ++t;
    }
    waitv<0>(); barrier_(); compute(t & (D - 1));
  }

  const int r0 = brow + wr * (BM / 2) + (lane >> 4) * 4;
  const int c0 = bcol + wc * (BN / 2) + (lane & 15);
#pragma unroll
  for (int m = 0; m < MF; ++m) {
#pragma unroll
    for (int j = 0; j < 4; ++j) {
      int row = r0 + m * 16 + j;
#pragma unroll
      for (int n = 0; n < NF; ++n) {
        int col = c0 + n * 16;
        float v = acc[m][n][j];
        int64_t idx = (int64_t)row * N + col;
        if (EPI == 0) {
          ((short*)Cp)[bz * sC + idx] = f2b(v);
        } else if (EPI == 3) {
          float r2 = v + e0[row] * e1[col] + e2[col];
          float xo = ((const float*)e3)[bz * sE + idx];
          ((float*)Cp)[bz * sC + idx] = xo * (1.0f + r2);
        } else if (EPI == 6) {
          ((short*)Cp)[bz * sC + idx] = f2b(bz == 2 ? sigm(v) : v);
        }
      }
    }
  }
}

// ---------------- launch ----------------
extern "C" void kernel_launch(void* const* d_in, const int* in_sizes, int n_in,
                              void* d_out, int out_size, void* d_ws,
                              size_t ws_size, hipStream_t stream) {
  const float* x   = (const float*)d_in[0];
  const float* rt  = (const float*)d_in[1];
  const float* td  = (const float*)d_in[2];
  const float* tf  = (const float*)d_in[3];
  const float* tmk = (const float*)d_in[4];
  const float* tmv = (const float*)d_in[5];
  const float* tmr = (const float*)d_in[6];
  const float* Wk  = (const float*)d_in[7];
  const float* Wv  = (const float*)d_in[8];
  const float* Wr  = (const float*)d_in[9];
  const float* Wo  = (const float*)d_in[10];
  const float* cmk = (const float*)d_in[11];
  const float* cmr = (const float*)d_in[12];
  const float* Wck = (const float*)d_in[13];
  const float* Wcv = (const float*)d_in[14];
  const float* Wcr = (const float*)d_in[15];
  const float* Wrm = (const float*)d_in[16];
  const float* brm = (const float*)d_in[17];
  const float* Wam = (const float*)d_in[18];
  const float* bam = (const float*)d_in[19];
  float* out = (float*)d_out;

  const size_t MB = 1ull << 20;
  uint8_t* W8 = (uint8_t*)d_ws;
  float* XC   = (float*)(W8);                        // 0-16 residual f32
  short* S1   = (short*)(W8 + 24 * MB);              // 24-32 xk / SRY / SRR
  short* S2   = (short*)(W8 + 32 * MB);              // 32-40 xv / xk2 / rtok,Mt
  short* S3   = (short*)(W8 + 40 * MB);              // 40-48 xr / xr2 / bWck
  short* bWcv = (short*)(W8 + 48 * MB);              // 48-56
  short* bWk  = (short*)(W8 + 56 * MB);              // 56-62
  short* bWo  = (short*)(W8 + 62 * MB);
  short* bWcr = (short*)(W8 + 64 * MB);
  short* bWrm = (short*)(W8 + 66 * MB);              // 0.5 MB
  short* bWam = (short*)(W8 + 66 * MB + 512 * 1024); // 0.5 MB
  short* KK   = (short*)(W8 + 67 * MB);              // 67-75
  short* VV   = (short*)(W8 + 75 * MB);              // 75-83
  short* RR   = (short*)(W8 + 83 * MB);              // 83-91
  float* Ca   = (float*)(W8 + 91 * MB);              // wkv temps 91-97
  float* Da   = (float*)(W8 + 92 * MB);
  float* Qa   = (float*)(W8 + 93 * MB);
  float* Aa   = (float*)(W8 + 94 * MB);
  float* Ba   = (float*)(W8 + 95 * MB);
  float* Pa   = (float*)(W8 + 96 * MB);
  short* SRY  = S1;
  short* xk2  = S2;
  short* xr2  = S3;
  short* SRR  = S1;
  short* bWck = S3;
  short* H16  = KK;                                  // 67-99 (32 MB)
  short* rtok = S2;                                  // 32-36 (tail)
  short* Mt   = (short*)(W8 + 36 * MB);              // 36-37 (tail)
  float* Sb   = (float*)(W8 + 99 * MB);              // 4 KB

  dim3 blk(256);
  dim3 blk512(512);

  // 0) ALL weight conversions + Wam row-sum in one launch
  cvt_all<<<5120, blk, 0, stream>>>(Wk, Wv, Wr, Wo, Wcr, Wcv, Wrm, Wam,
                                    bWk, bWk + 1048576, bWk + 2097152, bWo,
                                    bWcr, bWcv, bWrm, bWam, Sb);

  // 1) FUSED concat + ln1 + time-mix blends -> XC, S1, S2, S3
  ln_mix3<<<TB_ * TT_, blk, 0, stream>>>(x, rt, tmk, tmv, tmr, XC, S1, S2, S3);

  // 2) fused z=3 time-mix: KK/VV/RR (grid 768 = 3 blk/CU, D=2)
  gemm_bf16<128, 128, 6, 2, 3><<<dim3(8, 32, 3), blk, 0, stream>>>(
      S1, bWk, KK, 4096, 1024, 1024, 1024, 4194304, 1048576, 4194304,
      nullptr, nullptr, nullptr, nullptr, 0);
  // 3) wkv chunked scan -> SRY (=S1)
  wkv_p1<<<WKV_NCH * TB_ * 4, blk, 0, stream>>>(td, KK, VV, Ca, Da, Qa);
  wkv_p2<<<32, blk, 0, stream>>>(td, Ca, Da, Qa, Aa, Ba, Pa);
  wkv_p3<<<WKV_NCH * TB_ * 4, blk, 0, stream>>>(td, tf, KK, VV, RR, SRY,
                                                Aa, Ba, Pa);
  // 4) att: XC += lif(SRY*Wo^T)   (4-phase interleaved, 8 waves)
  gemm4p<4><<<dim3(8, 32), blk512, 0, stream>>>(
      SRY, bWo, XC, 4096, 1024, 1024, 1024, nullptr, nullptr, nullptr,
      nullptr);
  // 5) fused ln2+mix2 -> xk2(S2), xr2(S3)
  ln_mix2<<<TB_ * TT_, blk, 0, stream>>>(XC, cmk, cmr, xk2, xr2);
  // 6) SRR = sigm(xr2*Wcr^T) -> S1   (4-phase)
  gemm4p<1><<<dim3(8, 32), blk512, 0, stream>>>(
      xr2, bWcr, SRR, 4096, 1024, 1024, 1024, nullptr, nullptr, nullptr,
      nullptr);
  // 7) Wck -> bf16 into now-dead xr2 slot
  cvt_b<<<2048, blk, 0, stream>>>(Wck, bWck);
  // 8) H = relu^2(xk2*Wck^T) -> H16   (256^2 4-phase, grid 256 = 1 blk/CU)
  gemm256<2><<<dim3(16, 16), blk512, 0, stream>>>(
      xk2, bWck, H16, 4096, 4096, 1024, 1024);
  // 9) XC += lif(SRR*(H*Wcv^T))   (4-phase, K=4096)
  gemm4p<5><<<dim3(8, 32), blk512, 0, stream>>>(
      H16, bWcv, XC, 4096, 1024, 4096, 4096, nullptr, nullptr, nullptr, SRR);
  // 10) tail
  cvt_rtok<<<1024, blk, 0, stream>>>(XC, rtok);
  gemm_bf16<64, 64, 0, 2, 2><<<dim3(4, 4, 8), blk, 0, stream>>>(
      bWrm, rtok, Mt, 256, 256, 1024, 1024, 0, (int64_t)256 * 1024,
      (int64_t)256 * 256, nullptr, nullptr, nullptr, nullptr, 0);
  gemm_bf16<64, 64, 3, 2, 2><<<dim3(16, 4, 8), blk, 0, stream>>>(
      Mt, bWam, out, 256, 1024, 256, 256, (int64_t)256 * 256, 0,
      (int64_t)256 * 1024, brm, Sb, bam, XC, (int64_t)512 * 1024);
}

// Round 18
// 298.910 us; speedup vs baseline: 1.1642x; 1.0190x over previous
//
#include <hip/hip_runtime.h>
#include <hip/hip_bf16.h>
#include <math.h>
#include <stdint.h>

// B=8, P1=256 -> T=512 concat rows, C=1024, H=4096
#define TB_ 8
#define TT_ 512
#define TC_ 1024
#define WKV_NCH 32
#define WKV_L 16

typedef __attribute__((ext_vector_type(8))) short bf16x8;
typedef __attribute__((ext_vector_type(4))) short s16x4;
typedef __attribute__((ext_vector_type(4))) float f32x4;

__device__ __forceinline__ float b2f(short u) {
  union { unsigned int i; float f; } x;
  x.i = ((unsigned int)(unsigned short)u) << 16;
  return x.f;
}
__device__ __forceinline__ short f2b(float f) {
  __hip_bfloat16 h = __float2bfloat16(f);  // RNE
  return __builtin_bit_cast(short, h);
}
__device__ __forceinline__ float sigm(float x) { return 1.0f / (1.0f + expf(-x)); }

__device__ __forceinline__ float lif4(float a) {
  float v = 0.0f, acc = 0.0f;
#pragma unroll
  for (int i = 0; i < 4; ++i) {
    v += (a - v) * 0.5f;
    float s = (v >= 1.0f) ? 1.0f : 0.0f;
    acc += s;
    v *= (1.0f - s);
  }
  return acc * 0.25f;
}

__device__ __forceinline__ void gload16(const void* g, void* l) {
  __builtin_amdgcn_global_load_lds(
      (__attribute__((address_space(1))) void*)(g),
      (__attribute__((address_space(3))) void*)(l), 16, 0, 0);
}

template <int N>
__device__ __forceinline__ void waitv() {
  if constexpr (N == 0)  asm volatile("s_waitcnt vmcnt(0)" ::: "memory");
  else if constexpr (N == 2)  asm volatile("s_waitcnt vmcnt(2)" ::: "memory");
  else if constexpr (N == 4)  asm volatile("s_waitcnt vmcnt(4)" ::: "memory");
  else if constexpr (N == 8)  asm volatile("s_waitcnt vmcnt(8)" ::: "memory");
  else if constexpr (N == 12) asm volatile("s_waitcnt vmcnt(12)" ::: "memory");
  else static_assert(N == 0, "unsupported vmcnt");
}
__device__ __forceinline__ void barrier_() {
  asm volatile("s_barrier" ::: "memory");
}

// ---------------- elementwise kernels ----------------

// FUSED concat + ln1 + time-mix blends (one 256-thr block per row).
__global__ __launch_bounds__(256) void ln_mix3(
    const float* __restrict__ x, const float* __restrict__ rt,
    const float* __restrict__ tmk, const float* __restrict__ tmv,
    const float* __restrict__ tmr, float* __restrict__ xc,
    short* __restrict__ xk, short* __restrict__ xv, short* __restrict__ xr) {
  __shared__ float red[256];
  int row = blockIdx.x;
  int t = row & 511, b = row >> 9;
  int tid = threadIdx.x;
  const float* src = (t < 256) ? x + (int64_t)(b * 256 + t) * TC_
                               : rt + (int64_t)(t - 256) * TC_;
  float4 v = ((const float4*)src)[tid];
  ((float4*)(xc + (int64_t)row * TC_))[tid] = v;
  red[tid] = v.x + v.y + v.z + v.w;
  __syncthreads();
  for (int off = 128; off > 0; off >>= 1) {
    if (tid < off) red[tid] += red[tid + off];
    __syncthreads();
  }
  float mean = red[0] * (1.0f / 1024.0f);
  __syncthreads();
  float dx = v.x - mean, dy = v.y - mean, dz = v.z - mean, dw = v.w - mean;
  red[tid] = dx * dx + dy * dy + dz * dz + dw * dw;
  __syncthreads();
  for (int off = 128; off > 0; off >>= 1) {
    if (tid < off) red[tid] += red[tid + off];
    __syncthreads();
  }
  float rs = 1.0f / sqrtf(red[0] * (1.0f / 1024.0f) + 1e-6f);
  float c0 = dx * rs, c1 = dy * rs, c2 = dz * rs, c3 = dw * rs;
  float p0 = 0.f, p1 = 0.f, p2 = 0.f, p3 = 0.f;
  if (t > 0) {  // block-uniform
    int tp = t - 1;
    const float* srcp = (tp < 256) ? x + (int64_t)(b * 256 + tp) * TC_
                                   : rt + (int64_t)(tp - 256) * TC_;
    __syncthreads();
    float4 w4 = ((const float4*)srcp)[tid];
    red[tid] = w4.x + w4.y + w4.z + w4.w;
    __syncthreads();
    for (int off = 128; off > 0; off >>= 1) {
      if (tid < off) red[tid] += red[tid + off];
      __syncthreads();
    }
    float meanp = red[0] * (1.0f / 1024.0f);
    __syncthreads();
    float ex = w4.x - meanp, ey = w4.y - meanp, ez = w4.z - meanp,
          ew = w4.w - meanp;
    red[tid] = ex * ex + ey * ey + ez * ez + ew * ew;
    __syncthreads();
    for (int off = 128; off > 0; off >>= 1) {
      if (tid < off) red[tid] += red[tid + off];
      __syncthreads();
    }
    float rsp = 1.0f / sqrtf(red[0] * (1.0f / 1024.0f) + 1e-6f);
    p0 = ex * rsp; p1 = ey * rsp; p2 = ez * rsp; p3 = ew * rsp;
  }
  int c = tid * 4;
  int64_t o = (int64_t)row * TC_ + c;
  float m0, m1, m2, m3;
  s16x4 ov;
  m0 = tmk[c]; m1 = tmk[c + 1]; m2 = tmk[c + 2]; m3 = tmk[c + 3];
  ov.x = f2b(c0 * m0 + p0 * (1.0f - m0));
  ov.y = f2b(c1 * m1 + p1 * (1.0f - m1));
  ov.z = f2b(c2 * m2 + p2 * (1.0f - m2));
  ov.w = f2b(c3 * m3 + p3 * (1.0f - m3));
  *(s16x4*)(xk + o) = ov;
  m0 = tmv[c]; m1 = tmv[c + 1]; m2 = tmv[c + 2]; m3 = tmv[c + 3];
  ov.x = f2b(c0 * m0 + p0 * (1.0f - m0));
  ov.y = f2b(c1 * m1 + p1 * (1.0f - m1));
  ov.z = f2b(c2 * m2 + p2 * (1.0f - m2));
  ov.w = f2b(c3 * m3 + p3 * (1.0f - m3));
  *(s16x4*)(xv + o) = ov;
  m0 = tmr[c]; m1 = tmr[c + 1]; m2 = tmr[c + 2]; m3 = tmr[c + 3];
  ov.x = f2b(c0 * m0 + p0 * (1.0f - m0));
  ov.y = f2b(c1 * m1 + p1 * (1.0f - m1));
  ov.z = f2b(c2 * m2 + p2 * (1.0f - m2));
  ov.w = f2b(c3 * m3 + p3 * (1.0f - m3));
  *(s16x4*)(xr + o) = ov;
}

// fused ln2 + channel-mix blend (same recompute pattern).
__global__ __launch_bounds__(256) void ln_mix2(const float* __restrict__ xc,
                                               const float* __restrict__ cmk,
                                               const float* __restrict__ cmr,
                                               short* __restrict__ xk,
                                               short* __restrict__ xr) {
  __shared__ float red[256];
  int row = blockIdx.x;
  int t = row & 511;
  int tid = threadIdx.x;
  float4 v = ((const float4*)(xc + (int64_t)row * TC_))[tid];
  red[tid] = v.x + v.y + v.z + v.w;
  __syncthreads();
  for (int off = 128; off > 0; off >>= 1) {
    if (tid < off) red[tid] += red[tid + off];
    __syncthreads();
  }
  float mean = red[0] * (1.0f / 1024.0f);
  __syncthreads();
  float dx = v.x - mean, dy = v.y - mean, dz = v.z - mean, dw = v.w - mean;
  red[tid] = dx * dx + dy * dy + dz * dz + dw * dw;
  __syncthreads();
  for (int off = 128; off > 0; off >>= 1) {
    if (tid < off) red[tid] += red[tid + off];
    __syncthreads();
  }
  float rs = 1.0f / sqrtf(red[0] * (1.0f / 1024.0f) + 1e-6f);
  float c0 = dx * rs, c1 = dy * rs, c2 = dz * rs, c3 = dw * rs;
  float p0 = 0.f, p1 = 0.f, p2 = 0.f, p3 = 0.f;
  if (t > 0) {
    __syncthreads();
    float4 w4 = ((const float4*)(xc + (int64_t)(row - 1) * TC_))[tid];
    red[tid] = w4.x + w4.y + w4.z + w4.w;
    __syncthreads();
    for (int off = 128; off > 0; off >>= 1) {
      if (tid < off) red[tid] += red[tid + off];
      __syncthreads();
    }
    float meanp = red[0] * (1.0f / 1024.0f);
    __syncthreads();
    float ex = w4.x - meanp, ey = w4.y - meanp, ez = w4.z - meanp,
          ew = w4.w - meanp;
    red[tid] = ex * ex + ey * ey + ez * ez + ew * ew;
    __syncthreads();
    for (int off = 128; off > 0; off >>= 1) {
      if (tid < off) red[tid] += red[tid + off];
      __syncthreads();
    }
    float rsp = 1.0f / sqrtf(red[0] * (1.0f / 1024.0f) + 1e-6f);
    p0 = ex * rsp; p1 = ey * rsp; p2 = ez * rsp; p3 = ew * rsp;
  }
  int c = tid * 4;
  float k0 = cmk[c], k1 = cmk[c + 1], k2 = cmk[c + 2], k3 = cmk[c + 3];
  float r0 = cmr[c], r1 = cmr[c + 1], r2 = cmr[c + 2], r3 = cmr[c + 3];
  s16x4 ok, orr;
  ok.x = f2b(c0 * k0 + p0 * (1.0f - k0));
  ok.y = f2b(c1 * k1 + p1 * (1.0f - k1));
  ok.z = f2b(c2 * k2 + p2 * (1.0f - k2));
  ok.w = f2b(c3 * k3 + p3 * (1.0f - k3));
  orr.x = f2b(c0 * r0 + p0 * (1.0f - r0));
  orr.y = f2b(c1 * r1 + p1 * (1.0f - r1));
  orr.z = f2b(c2 * r2 + p2 * (1.0f - r2));
  orr.w = f2b(c3 * r3 + p3 * (1.0f - r3));
  *(s16x4*)(xk + (int64_t)row * TC_ + c) = ok;
  *(s16x4*)(xr + (int64_t)row * TC_ + c) = orr;
}

// f32 -> bf16, 8 elems/thread
__global__ __launch_bounds__(256) void cvt_b(const float* __restrict__ src,
                                             short* __restrict__ dst) {
  int64_t i = (int64_t)(blockIdx.x * 256 + threadIdx.x) * 8;
  float4 a = *(const float4*)(src + i);
  float4 b = *(const float4*)(src + i + 4);
  bf16x8 o;
  o[0] = f2b(a.x); o[1] = f2b(a.y); o[2] = f2b(a.z); o[3] = f2b(a.w);
  o[4] = f2b(b.x); o[5] = f2b(b.y); o[6] = f2b(b.z); o[7] = f2b(b.w);
  *(bf16x8*)(dst + i) = o;
}

// rtok rows (per b: rows 256..511 of XC) f32 -> bf16 contiguous (B,256,C)
__global__ __launch_bounds__(256) void cvt_rtok(const float* __restrict__ xc,
                                                short* __restrict__ dst) {
  int i = blockIdx.x * 256 + threadIdx.x;  // short8 idx
  int b = i >> 15;
  int rem = i & 32767;
  const float* s = xc + (int64_t)b * 524288 + 262144 + (int64_t)rem * 8;
  float4 a = *(const float4*)s;
  float4 c = *(const float4*)(s + 4);
  bf16x8 o;
  o[0] = f2b(a.x); o[1] = f2b(a.y); o[2] = f2b(a.z); o[3] = f2b(a.w);
  o[4] = f2b(c.x); o[5] = f2b(c.y); o[6] = f2b(c.z); o[7] = f2b(c.w);
  *(bf16x8*)(dst + (int64_t)i * 8) = o;
}

// ONE launch: convert 8 weight arrays f32->bf16 + fused Wam row-sum.
__global__ __launch_bounds__(256) void cvt_all(
    const float* __restrict__ Wk, const float* __restrict__ Wv,
    const float* __restrict__ Wr, const float* __restrict__ Wo,
    const float* __restrict__ Wcr, const float* __restrict__ Wcv,
    const float* __restrict__ Wrm, const float* __restrict__ Wam,
    short* __restrict__ bWk, short* __restrict__ bWv, short* __restrict__ bWr,
    short* __restrict__ bWo, short* __restrict__ bWcr, short* __restrict__ bWcv,
    short* __restrict__ bWrm, short* __restrict__ bWam,
    float* __restrict__ S) {
  int bid = blockIdx.x;
  if (bid >= 4864) {
    int row = (bid - 4864) * 4 + (threadIdx.x >> 6);
    int lane = threadIdx.x & 63;
    float4 v = ((const float4*)(Wam + (int64_t)row * 256))[lane];
    float s = v.x + v.y + v.z + v.w;
    for (int off = 32; off > 0; off >>= 1) s += __shfl_down(s, off);
    if (lane == 0) S[row] = s;
    return;
  }
  const float* src; short* dst; int base;
  if (bid < 512)       { src = Wk;  dst = bWk;  base = bid; }
  else if (bid < 1024) { src = Wv;  dst = bWv;  base = bid - 512; }
  else if (bid < 1536) { src = Wr;  dst = bWr;  base = bid - 1024; }
  else if (bid < 2048) { src = Wo;  dst = bWo;  base = bid - 1536; }
  else if (bid < 2560) { src = Wcr; dst = bWcr; base = bid - 2048; }
  else if (bid < 4608) { src = Wcv; dst = bWcv; base = bid - 2560; }
  else if (bid < 4736) { src = Wrm; dst = bWrm; base = bid - 4608; }
  else                 { src = Wam; dst = bWam; base = bid - 4736; }
  int64_t i = ((int64_t)base * 256 + threadIdx.x) * 8;
  float4 a = *(const float4*)(src + i);
  float4 b = *(const float4*)(src + i + 4);
  bf16x8 o;
  o[0] = f2b(a.x); o[1] = f2b(a.y); o[2] = f2b(a.z); o[3] = f2b(a.w);
  o[4] = f2b(b.x); o[5] = f2b(b.y); o[6] = f2b(b.z); o[7] = f2b(b.w);
  *(bf16x8*)(dst + i) = o;
}

// ---------------- wkv chunked parallel scan ----------------
__global__ __launch_bounds__(256) void wkv_p1(const float* __restrict__ td,
                                              const short* __restrict__ K,
                                              const short* __restrict__ V,
                                              float* __restrict__ Ca,
                                              float* __restrict__ Da,
                                              float* __restrict__ Qa) {
  int bx = blockIdx.x;
  int ch = bx >> 5;
  int b = (bx >> 2) & 7;
  int c = (bx & 3) * 256 + threadIdx.x;
  float w = -expf(td[c]);
  float aa = 0.0f, bb = 0.0f, pp = -1e38f;
  int64_t base = ((int64_t)b * TT_ + ch * WKV_L) * TC_ + c;
#pragma unroll
  for (int t = 0; t < WKV_L; ++t) {
    int64_t o = base + (int64_t)t * TC_;
    float kt = b2f(K[o]), vt = b2f(V[o]);
    float ww2 = pp + w;
    float p2 = fmaxf(ww2, kt);
    float e1 = expf(ww2 - p2);
    float e2 = expf(kt - p2);
    aa = e1 * aa + e2 * vt;
    bb = e1 * bb + e2;
    pp = p2;
  }
  int idx = ch * 8192 + b * 1024 + c;
  Ca[idx] = aa; Da[idx] = bb; Qa[idx] = pp;
}

__global__ __launch_bounds__(256) void wkv_p2(const float* __restrict__ td,
                                              const float* __restrict__ Ca,
                                              const float* __restrict__ Da,
                                              const float* __restrict__ Qa,
                                              float* __restrict__ Aa,
                                              float* __restrict__ Ba,
                                              float* __restrict__ Pa) {
  int i = blockIdx.x * 256 + threadIdx.x;
  int c = i & (TC_ - 1);
  float wL = -expf(td[c]) * (float)WKV_L;
  float aa = 0.0f, bb = 0.0f, pp = -1e38f;
#pragma unroll 4
  for (int ch = 0; ch < WKV_NCH; ++ch) {
    int idx = ch * 8192 + i;
    Aa[idx] = aa; Ba[idx] = bb; Pa[idx] = pp;
    float ppw = pp + wL;
    float q = Qa[idx];
    float p2 = fmaxf(ppw, q);
    float ea = expf(ppw - p2);
    float eb = expf(q - p2);
    aa = aa * ea + Ca[idx] * eb;
    bb = bb * ea + Da[idx] * eb;
    pp = p2;
  }
}

__global__ __launch_bounds__(256) void wkv_p3(const float* __restrict__ td,
                                              const float* __restrict__ tf,
                                              const short* __restrict__ K,
                                              const short* __restrict__ V,
                                              const short* __restrict__ SR,
                                              short* __restrict__ SRY,
                                              const float* __restrict__ Aa,
                                              const float* __restrict__ Ba,
                                              const float* __restrict__ Pa) {
  int bx = blockIdx.x;
  int ch = bx >> 5;
  int b = (bx >> 2) & 7;
  int c = (bx & 3) * 256 + threadIdx.x;
  float w = -expf(td[c]);
  float u = tf[c];
  int idx = ch * 8192 + b * 1024 + c;
  float aa = Aa[idx], bb = Ba[idx], pp = Pa[idx];
  int64_t base = ((int64_t)b * TT_ + ch * WKV_L) * TC_ + c;
#pragma unroll
  for (int t = 0; t < WKV_L; ++t) {
    int64_t o = base + (int64_t)t * TC_;
    float kt = b2f(K[o]), vt = b2f(V[o]);
    float ww = u + kt;
    float p = fmaxf(pp, ww);
    float E1 = expf(pp - p);
    float E2 = expf(ww - p);
    float y = (E1 * aa + E2 * vt) / (E1 * bb + E2);
    SRY[o] = f2b(y * b2f(SR[o]));
    float ww2 = pp + w;
    float p2 = fmaxf(ww2, kt);
    float e1 = expf(ww2 - p2);
    float e2 = expf(kt - p2);
    aa = e1 * aa + e2 * vt;
    bb = e1 * bb + e2;
    pp = p2;
  }
}

// ---------------- 4-phase interleaved MFMA GEMM, 128x128 (N=1024) -------
// (R16-proven.) 8 waves, BK=64, dbuf LDS, counted vmcnt at P1/P3.
// EPI: 1 sigmoid bf16; 4 XC += lif4(acc); 5 XC += lif4(acc * srr(e3)).
template <int EPI>
__global__ __launch_bounds__(512, 1) void gemm4p(
    const short* __restrict__ A, const short* __restrict__ B,
    void* __restrict__ Cp, int M, int N, int K, int Kst,
    const float* __restrict__ e0, const float* __restrict__ e1,
    const float* __restrict__ e2, const void* __restrict__ e3) {
  __shared__ short lds[2 * 32768];
  const int tid = threadIdx.x;

  const unsigned gx = gridDim.x, gy = gridDim.y;
  const unsigned nwg = gx * gy;
  const unsigned lin = blockIdx.x + gx * blockIdx.y;
  const unsigned cs = nwg >> 3;
  const unsigned nl = (lin & 7) * cs + (lin >> 3);
  const unsigned bxs = nl % gx;
  const unsigned bys = nl / gx;

  const int brow = bys * 128;
  const int bcol = bxs * 128;

  const int srow = ((tid >> 6) << 4) + (tid & 15);
  const int skc = ((tid >> 4) & 3) * 8;
  const short* gA = A + (int64_t)(brow + srow) * Kst + skc;
  const short* gB = B + (int64_t)(bcol + srow) * Kst + skc;

  const int lane = tid & 63, wid = tid >> 6;
  const int wr = wid >> 2, wc = wid & 3;

  f32x4 acc[4][2] = {};

#define RD_A(rb, kh, m) \
  (*(const bf16x8*)(lds + (rb) * 32768 + (kh) * 8192 + (wr * 4 + (m)) * 512 + lane * 8))
#define RD_B(rb, kh, n) \
  (*(const bf16x8*)(lds + (rb) * 32768 + 16384 + (kh) * 8192 + (wc * 2 + (n)) * 512 + lane * 8))
#define ST_A(sb, kh, kt) \
  gload16(gA + (kt) * 64 + (kh) * 32, lds + (sb) * 32768 + (kh) * 8192 + tid * 8)
#define ST_B(sb, kh, kt) \
  gload16(gB + (kt) * 64 + (kh) * 32, lds + (sb) * 32768 + 16384 + (kh) * 8192 + tid * 8)
#define MM(am, bn, i, j) \
  acc[i][j] = __builtin_amdgcn_mfma_f32_16x16x32_bf16(am, bn, acc[i][j], 0, 0, 0)

  const int nt = K / 64;
  ST_A(0, 0, 0); ST_B(0, 0, 0); ST_A(0, 1, 0); ST_B(0, 1, 0);
  waitv<2>();
  barrier_();

  for (int t = 0; t < nt - 1; ++t) {
    const int rb = t & 1, sb = rb ^ 1, kn = t + 1;
    {
      bf16x8 a0 = RD_A(rb, 0, 0), a1 = RD_A(rb, 0, 1);
      bf16x8 b0 = RD_B(rb, 0, 0), b1 = RD_B(rb, 0, 1);
      ST_A(sb, 0, kn);
      MM(a0, b0, 0, 0); MM(a0, b1, 0, 1); MM(a1, b0, 1, 0); MM(a1, b1, 1, 1);
      barrier_();
      bf16x8 a2 = RD_A(rb, 0, 2), a3 = RD_A(rb, 0, 3);
      ST_B(sb, 0, kn);
      MM(a2, b0, 2, 0); MM(a2, b1, 2, 1); MM(a3, b0, 3, 0); MM(a3, b1, 3, 1);
      waitv<2>();
      barrier_();
    }
    {
      bf16x8 a0 = RD_A(rb, 1, 0), a1 = RD_A(rb, 1, 1);
      bf16x8 b0 = RD_B(rb, 1, 0), b1 = RD_B(rb, 1, 1);
      ST_A(sb, 1, kn);
      MM(a0, b0, 0, 0); MM(a0, b1, 0, 1); MM(a1, b0, 1, 0); MM(a1, b1, 1, 1);
      barrier_();
      bf16x8 a2 = RD_A(rb, 1, 2), a3 = RD_A(rb, 1, 3);
      ST_B(sb, 1, kn);
      MM(a2, b0, 2, 0); MM(a2, b1, 2, 1); MM(a3, b0, 3, 0); MM(a3, b1, 3, 1);
      waitv<2>();
      barrier_();
    }
  }
  {
    waitv<0>();
    barrier_();
    const int rb = (nt - 1) & 1;
#pragma unroll
    for (int kh = 0; kh < 2; ++kh) {
      bf16x8 a0 = RD_A(rb, kh, 0), a1 = RD_A(rb, kh, 1);
      bf16x8 a2 = RD_A(rb, kh, 2), a3 = RD_A(rb, kh, 3);
      bf16x8 b0 = RD_B(rb, kh, 0), b1 = RD_B(rb, kh, 1);
      MM(a0, b0, 0, 0); MM(a0, b1, 0, 1); MM(a1, b0, 1, 0); MM(a1, b1, 1, 1);
      MM(a2, b0, 2, 0); MM(a2, b1, 2, 1); MM(a3, b0, 3, 0); MM(a3, b1, 3, 1);
    }
  }
#undef RD_A
#undef RD_B
#undef ST_A
#undef ST_B
#undef MM

  const int r0 = brow + wr * 64 + (lane >> 4) * 4;
  const int c0 = bcol + wc * 32 + (lane & 15);
#pragma unroll
  for (int m = 0; m < 4; ++m) {
#pragma unroll
    for (int j = 0; j < 4; ++j) {
      int row = r0 + m * 16 + j;
#pragma unroll
      for (int n = 0; n < 2; ++n) {
        int col = c0 + n * 16;
        float v = acc[m][n][j];
        int64_t idx = (int64_t)row * N + col;
        if (EPI == 1) {
          ((short*)Cp)[idx] = f2b(sigm(v));
        } else if (EPI == 4) {
          float* XC = (float*)Cp;
          XC[idx] = XC[idx] + lif4(v);
        } else if (EPI == 5) {
          float* XC = (float*)Cp;
          float srr = b2f(((const short*)e3)[idx]);
          XC[idx] = XC[idx] + lif4(v * srr);
        }
      }
    }
  }
}

// ---------------- 4-phase interleaved MFMA GEMM, 256x256 ----------------
// (R17-proven on H.) 8 waves (2Mx4N, each owns 128x64), BK=64, dbuf 128 KB
// LDS, counted vmcnt(4) at P1/P3. Now batched (z) for the time-mix triple.
// EPI: 2 relu^2 -> bf16; 6 z-select (bz==2 ? sigmoid : plain) -> bf16.
template <int EPI>
__global__ __launch_bounds__(512, 1) void gemm256(
    const short* __restrict__ A, const short* __restrict__ B,
    void* __restrict__ Cp, int M, int N, int K, int Kst,
    int64_t sA, int64_t sB, int64_t sC) {
  __shared__ short lds[2 * 32768];  // 2 x 64KB: [Ah0 16K][Ah1][Bh0][Bh1]
  const int tid = threadIdx.x;

  const unsigned gx = gridDim.x, gy = gridDim.y;
  const unsigned nwg = gx * gy * gridDim.z;  // must be %8==0
  const unsigned lin = blockIdx.x + gx * (blockIdx.y + gy * blockIdx.z);
  const unsigned cs = nwg >> 3;
  const unsigned nl = (lin & 7) * cs + (lin >> 3);
  const unsigned bxs = nl % gx;
  const unsigned tmp = nl / gx;
  const unsigned bys = tmp % gy;
  const unsigned bz = tmp / gy;

  const int brow = bys * 256;
  const int bcol = bxs * 256;
  const short* Ab = A + bz * sA;
  const short* Bb = B + bz * sB;

  const short* gA[2];
  const short* gB[2];
  int loff[2];
#pragma unroll
  for (int c = 0; c < 2; ++c) {
    int p = c * 512 + tid;
    int u = p >> 6, s = p & 63;
    gA[c] = Ab + (int64_t)(brow + u * 16 + (s & 15)) * Kst + (s >> 4) * 8;
    gB[c] = Bb + (int64_t)(bcol + u * 16 + (s & 15)) * Kst + (s >> 4) * 8;
    loff[c] = p * 8;
  }

  const int lane = tid & 63, wid = tid >> 6;
  const int wr = wid >> 2, wc = wid & 3;

  f32x4 acc[8][4] = {};

#define RD_A(rb, kh, m) \
  (*(const bf16x8*)(lds + (rb) * 32768 + (kh) * 8192 + (wr * 8 + (m)) * 512 + lane * 8))
#define RD_B(rb, kh, n) \
  (*(const bf16x8*)(lds + (rb) * 32768 + 16384 + (kh) * 8192 + (wc * 4 + (n)) * 512 + lane * 8))
#define ST_A(sb, kh, kt)                                                     \
  {                                                                          \
    gload16(gA[0] + (kt) * 64 + (kh) * 32,                                   \
            lds + (sb) * 32768 + (kh) * 8192 + loff[0]);                     \
    gload16(gA[1] + (kt) * 64 + (kh) * 32,                                   \
            lds + (sb) * 32768 + (kh) * 8192 + loff[1]);                     \
  }
#define ST_B(sb, kh, kt)                                                     \
  {                                                                          \
    gload16(gB[0] + (kt) * 64 + (kh) * 32,                                   \
            lds + (sb) * 32768 + 16384 + (kh) * 8192 + loff[0]);             \
    gload16(gB[1] + (kt) * 64 + (kh) * 32,                                   \
            lds + (sb) * 32768 + 16384 + (kh) * 8192 + loff[1]);             \
  }
#define MM(am, bn, i, j) \
  acc[i][j] = __builtin_amdgcn_mfma_f32_16x16x32_bf16(am, bn, acc[i][j], 0, 0, 0)

  const int nt = K / 64;
  ST_A(0, 0, 0); ST_B(0, 0, 0); ST_A(0, 1, 0); ST_B(0, 1, 0);
  waitv<4>();
  barrier_();

  for (int t = 0; t < nt - 1; ++t) {
    const int rb = t & 1, sb = rb ^ 1, kn = t + 1;
    bf16x8 b0, b1, b2, b3;
    {
      bf16x8 a0 = RD_A(rb, 0, 0), a1 = RD_A(rb, 0, 1);
      bf16x8 a2 = RD_A(rb, 0, 2), a3 = RD_A(rb, 0, 3);
      b0 = RD_B(rb, 0, 0); b1 = RD_B(rb, 0, 1);
      b2 = RD_B(rb, 0, 2); b3 = RD_B(rb, 0, 3);
      ST_A(sb, 0, kn);
      MM(a0, b0, 0, 0); MM(a0, b1, 0, 1); MM(a0, b2, 0, 2); MM(a0, b3, 0, 3);
      MM(a1, b0, 1, 0); MM(a1, b1, 1, 1); MM(a1, b2, 1, 2); MM(a1, b3, 1, 3);
      MM(a2, b0, 2, 0); MM(a2, b1, 2, 1); MM(a2, b2, 2, 2); MM(a2, b3, 2, 3);
      MM(a3, b0, 3, 0); MM(a3, b1, 3, 1); MM(a3, b2, 3, 2); MM(a3, b3, 3, 3);
      barrier_();
    }
    {
      bf16x8 a4 = RD_A(rb, 0, 4), a5 = RD_A(rb, 0, 5);
      bf16x8 a6 = RD_A(rb, 0, 6), a7 = RD_A(rb, 0, 7);
      ST_B(sb, 0, kn);
      MM(a4, b0, 4, 0); MM(a4, b1, 4, 1); MM(a4, b2, 4, 2); MM(a4, b3, 4, 3);
      MM(a5, b0, 5, 0); MM(a5, b1, 5, 1); MM(a5, b2, 5, 2); MM(a5, b3, 5, 3);
      MM(a6, b0, 6, 0); MM(a6, b1, 6, 1); MM(a6, b2, 6, 2); MM(a6, b3, 6, 3);
      MM(a7, b0, 7, 0); MM(a7, b1, 7, 1); MM(a7, b2, 7, 2); MM(a7, b3, 7, 3);
      waitv<4>();
      barrier_();
    }
    {
      bf16x8 a0 = RD_A(rb, 1, 0), a1 = RD_A(rb, 1, 1);
      bf16x8 a2 = RD_A(rb, 1, 2), a3 = RD_A(rb, 1, 3);
      b0 = RD_B(rb, 1, 0); b1 = RD_B(rb, 1, 1);
      b2 = RD_B(rb, 1, 2); b3 = RD_B(rb, 1, 3);
      ST_A(sb, 1, kn);
      MM(a0, b0, 0, 0); MM(a0, b1, 0, 1); MM(a0, b2, 0, 2); MM(a0, b3, 0, 3);
      MM(a1, b0, 1, 0); MM(a1, b1, 1, 1); MM(a1, b2, 1, 2); MM(a1, b3, 1, 3);
      MM(a2, b0, 2, 0); MM(a2, b1, 2, 1); MM(a2, b2, 2, 2); MM(a2, b3, 2, 3);
      MM(a3, b0, 3, 0); MM(a3, b1, 3, 1); MM(a3, b2, 3, 2); MM(a3, b3, 3, 3);
      barrier_();
    }
    {
      bf16x8 a4 = RD_A(rb, 1, 4), a5 = RD_A(rb, 1, 5);
      bf16x8 a6 = RD_A(rb, 1, 6), a7 = RD_A(rb, 1, 7);
      ST_B(sb, 1, kn);
      MM(a4, b0, 4, 0); MM(a4, b1, 4, 1); MM(a4, b2, 4, 2); MM(a4, b3, 4, 3);
      MM(a5, b0, 5, 0); MM(a5, b1, 5, 1); MM(a5, b2, 5, 2); MM(a5, b3, 5, 3);
      MM(a6, b0, 6, 0); MM(a6, b1, 6, 1); MM(a6, b2, 6, 2); MM(a6, b3, 6, 3);
      MM(a7, b0, 7, 0); MM(a7, b1, 7, 1); MM(a7, b2, 7, 2); MM(a7, b3, 7, 3);
      waitv<4>();
      barrier_();
    }
  }
  {
    waitv<0>();
    barrier_();
    const int rb = (nt - 1) & 1;
#pragma unroll
    for (int kh = 0; kh < 2; ++kh) {
      bf16x8 b0 = RD_B(rb, kh, 0), b1 = RD_B(rb, kh, 1);
      bf16x8 b2 = RD_B(rb, kh, 2), b3 = RD_B(rb, kh, 3);
#pragma unroll
      for (int m = 0; m < 8; ++m) {
        bf16x8 am = RD_A(rb, kh, m);
        MM(am, b0, m, 0); MM(am, b1, m, 1);
        MM(am, b2, m, 2); MM(am, b3, m, 3);
      }
    }
  }
#undef RD_A
#undef RD_B
#undef ST_A
#undef ST_B
#undef MM

  const int r0 = brow + wr * 128 + (lane >> 4) * 4;
  const int c0 = bcol + wc * 64 + (lane & 15);
#pragma unroll
  for (int m = 0; m < 8; ++m) {
#pragma unroll
    for (int j = 0; j < 4; ++j) {
      int row = r0 + m * 16 + j;
#pragma unroll
      for (int n = 0; n < 4; ++n) {
        int col = c0 + n * 16;
        float v = acc[m][n][j];
        int64_t idx = bz * sC + (int64_t)row * N + col;
        if (EPI == 2) {
          v = fmaxf(v, 0.0f);
          ((short*)Cp)[idx] = f2b(v * v);
        } else if (EPI == 6) {
          ((short*)Cp)[idx] = f2b(bz == 2 ? sigm(v) : v);
        }
      }
    }
  }
}

// ---------------- LDS MFMA GEMM (2-barrier path: tails) -----------------
template <int BM, int BN, int EPI, int D, int MINW>
__global__ __launch_bounds__(256, MINW) void gemm_bf16(
    const short* __restrict__ A, const short* __restrict__ B,
    void* __restrict__ Cp, int M, int N, int K, int Kst,
    int64_t sA, int64_t sB, int64_t sC,
    const float* __restrict__ e0, const float* __restrict__ e1,
    const float* __restrict__ e2, const void* __restrict__ e3, int64_t sE) {
  constexpr int MF = BM / 32;
  constexpr int NF = BN / 32;
  constexpr int ASLOT = BM / 64;
  constexpr int BSLOT = BN / 64;
  constexpr int NL = ASLOT + BSLOT;
  constexpr int SBUF = (BM + BN) * 32;
  __shared__ short lds[D * SBUF];
  const int tid = threadIdx.x;

  const unsigned gx = gridDim.x, gy = gridDim.y;
  const unsigned nwg = gx * gy * gridDim.z;
  const unsigned lin = blockIdx.x + gx * (blockIdx.y + gy * blockIdx.z);
  const unsigned cs = nwg >> 3;
  const unsigned nl = (lin & 7) * cs + (lin >> 3);
  const unsigned bxs = nl % gx;
  const unsigned tmp = nl / gx;
  const unsigned bys = tmp % gy;
  const unsigned bz = tmp / gy;

  const int brow = bys * BM;
  const int bcol = bxs * BN;
  const short* Ab = A + bz * sA;
  const short* Bb = B + bz * sB;

  const int srow = ((tid >> 6) << 4) + (tid & 15);
  const int skc = ((tid >> 4) & 3) * 8;
  const short* gA[ASLOT];
  const short* gB[BSLOT];
#pragma unroll
  for (int s = 0; s < ASLOT; ++s)
    gA[s] = Ab + (int64_t)(brow + s * 64 + srow) * Kst + skc;
#pragma unroll
  for (int s = 0; s < BSLOT; ++s)
    gB[s] = Bb + (int64_t)(bcol + s * 64 + srow) * Kst + skc;

  const int lane = tid & 63, wid = tid >> 6;
  const int wr = wid >> 1, wc = wid & 1;

  f32x4 acc[MF][NF] = {};

  auto stage = [&](int buf, int k0) {
    short* d = lds + buf * SBUF;
#pragma unroll
    for (int s = 0; s < ASLOT; ++s)
      gload16(gA[s] + k0, d + s * 2048 + tid * 8);
#pragma unroll
    for (int s = 0; s < BSLOT; ++s)
      gload16(gB[s] + k0, d + BM * 32 + s * 2048 + tid * 8);
  };
  auto compute = [&](int buf) {
    const short* base = lds + buf * SBUF;
    bf16x8 af[MF], bfv[NF];
#pragma unroll
    for (int m = 0; m < MF; ++m)
      af[m] = *(const bf16x8*)(base + (wr * MF + m) * 512 + lane * 8);
#pragma unroll
    for (int n = 0; n < NF; ++n)
      bfv[n] = *(const bf16x8*)(base + BM * 32 + (wc * NF + n) * 512 + lane * 8);
#pragma unroll
    for (int m = 0; m < MF; ++m)
#pragma unroll
      for (int n = 0; n < NF; ++n)
        acc[m][n] = __builtin_amdgcn_mfma_f32_16x16x32_bf16(af[m], bfv[n],
                                                            acc[m][n], 0, 0, 0);
  };

  const int nst = K / 32;
#pragma unroll
  for (int d = 0; d < D - 1; ++d) stage(d, d * 32);
  for (int t = 0; t <= nst - D; ++t) {
    stage((t + D - 1) & (D - 1), (t + D - 1) * 32);
    waitv<(D - 1) * NL>();
    barrier_();
    compute(t & (D - 1));
    barrier_();
  }
  {
    int t = nst - D + 1;
    if constexpr (D >= 4) {
      waitv<2 * NL>(); barrier_(); compute(t & (D - 1)); barrier_(); ++t;
      waitv<1 * NL>(); barrier_(); compute(t & (D - 1)); barrier_(); ++t;
    }
    waitv<0>(); barrier_(); compute(t & (D - 1));
  }

  const int r0 = brow + wr * (BM / 2) + (lane >> 4) * 4;
  const int c0 = bcol + wc * (BN / 2) + (lane & 15);
#pragma unroll
  for (int m = 0; m < MF; ++m) {
#pragma unroll
    for (int j = 0; j < 4; ++j) {
      int row = r0 + m * 16 + j;
#pragma unroll
      for (int n = 0; n < NF; ++n) {
        int col = c0 + n * 16;
        float v = acc[m][n][j];
        int64_t idx = (int64_t)row * N + col;
        if (EPI == 0) {
          ((short*)Cp)[bz * sC + idx] = f2b(v);
        } else if (EPI == 3) {
          float r2 = v + e0[row] * e1[col] + e2[col];
          float xo = ((const float*)e3)[bz * sE + idx];
          ((float*)Cp)[bz * sC + idx] = xo * (1.0f + r2);
        }
      }
    }
  }
}

// ---------------- launch ----------------
extern "C" void kernel_launch(void* const* d_in, const int* in_sizes, int n_in,
                              void* d_out, int out_size, void* d_ws,
                              size_t ws_size, hipStream_t stream) {
  const float* x   = (const float*)d_in[0];
  const float* rt  = (const float*)d_in[1];
  const float* td  = (const float*)d_in[2];
  const float* tf  = (const float*)d_in[3];
  const float* tmk = (const float*)d_in[4];
  const float* tmv = (const float*)d_in[5];
  const float* tmr = (const float*)d_in[6];
  const float* Wk  = (const float*)d_in[7];
  const float* Wv  = (const float*)d_in[8];
  const float* Wr  = (const float*)d_in[9];
  const float* Wo  = (const float*)d_in[10];
  const float* cmk = (const float*)d_in[11];
  const float* cmr = (const float*)d_in[12];
  const float* Wck = (const float*)d_in[13];
  const float* Wcv = (const float*)d_in[14];
  const float* Wcr = (const float*)d_in[15];
  const float* Wrm = (const float*)d_in[16];
  const float* brm = (const float*)d_in[17];
  const float* Wam = (const float*)d_in[18];
  const float* bam = (const float*)d_in[19];
  float* out = (float*)d_out;

  const size_t MB = 1ull << 20;
  uint8_t* W8 = (uint8_t*)d_ws;
  float* XC   = (float*)(W8);                        // 0-16 residual f32
  short* S1   = (short*)(W8 + 24 * MB);              // 24-32 xk / SRY / SRR
  short* S2   = (short*)(W8 + 32 * MB);              // 32-40 xv / xk2 / rtok,Mt
  short* S3   = (short*)(W8 + 40 * MB);              // 40-48 xr / xr2 / bWck
  short* bWcv = (short*)(W8 + 48 * MB);              // 48-56
  short* bWk  = (short*)(W8 + 56 * MB);              // 56-62
  short* bWo  = (short*)(W8 + 62 * MB);
  short* bWcr = (short*)(W8 + 64 * MB);
  short* bWrm = (short*)(W8 + 66 * MB);              // 0.5 MB
  short* bWam = (short*)(W8 + 66 * MB + 512 * 1024); // 0.5 MB
  short* KK   = (short*)(W8 + 67 * MB);              // 67-75
  short* VV   = (short*)(W8 + 75 * MB);              // 75-83
  short* RR   = (short*)(W8 + 83 * MB);              // 83-91
  float* Ca   = (float*)(W8 + 91 * MB);              // wkv temps 91-97
  float* Da   = (float*)(W8 + 92 * MB);
  float* Qa   = (float*)(W8 + 93 * MB);
  float* Aa   = (float*)(W8 + 94 * MB);
  float* Ba   = (float*)(W8 + 95 * MB);
  float* Pa   = (float*)(W8 + 96 * MB);
  short* SRY  = S1;
  short* xk2  = S2;
  short* xr2  = S3;
  short* SRR  = S1;
  short* bWck = S3;
  short* H16  = KK;                                  // 67-99 (32 MB)
  short* rtok = S2;                                  // 32-36 (tail)
  short* Mt   = (short*)(W8 + 36 * MB);              // 36-37 (tail)
  float* Sb   = (float*)(W8 + 99 * MB);              // 4 KB

  dim3 blk(256);
  dim3 blk512(512);

  // 0) ALL weight conversions + Wam row-sum in one launch
  cvt_all<<<5120, blk, 0, stream>>>(Wk, Wv, Wr, Wo, Wcr, Wcv, Wrm, Wam,
                                    bWk, bWk + 1048576, bWk + 2097152, bWo,
                                    bWcr, bWcv, bWrm, bWam, Sb);

  // 1) FUSED concat + ln1 + time-mix blends -> XC, S1, S2, S3
  ln_mix3<<<TB_ * TT_, blk, 0, stream>>>(x, rt, tmk, tmv, tmr, XC, S1, S2, S3);

  // 2) fused z=3 time-mix: KK/VV/RR   (256^2 4-phase, grid 192, z-batched)
  gemm256<6><<<dim3(4, 16, 3), blk512, 0, stream>>>(
      S1, bWk, KK, 4096, 1024, 1024, 1024, 4194304, 1048576, 4194304);
  // 3) wkv chunked scan -> SRY (=S1)
  wkv_p1<<<WKV_NCH * TB_ * 4, blk, 0, stream>>>(td, KK, VV, Ca, Da, Qa);
  wkv_p2<<<32, blk, 0, stream>>>(td, Ca, Da, Qa, Aa, Ba, Pa);
  wkv_p3<<<WKV_NCH * TB_ * 4, blk, 0, stream>>>(td, tf, KK, VV, RR, SRY,
                                                Aa, Ba, Pa);
  // 4) att: XC += lif(SRY*Wo^T)   (4-phase interleaved, 8 waves)
  gemm4p<4><<<dim3(8, 32), blk512, 0, stream>>>(
      SRY, bWo, XC, 4096, 1024, 1024, 1024, nullptr, nullptr, nullptr,
      nullptr);
  // 5) fused ln2+mix2 -> xk2(S2), xr2(S3)
  ln_mix2<<<TB_ * TT_, blk, 0, stream>>>(XC, cmk, cmr, xk2, xr2);
  // 6) SRR = sigm(xr2*Wcr^T) -> S1   (4-phase)
  gemm4p<1><<<dim3(8, 32), blk512, 0, stream>>>(
      xr2, bWcr, SRR, 4096, 1024, 1024, 1024, nullptr, nullptr, nullptr,
      nullptr);
  // 7) Wck -> bf16 into now-dead xr2 slot
  cvt_b<<<2048, blk, 0, stream>>>(Wck, bWck);
  // 8) H = relu^2(xk2*Wck^T) -> H16   (256^2 4-phase, grid 256 = 1 blk/CU)
  gemm256<2><<<dim3(16, 16), blk512, 0, stream>>>(
      xk2, bWck, H16, 4096, 4096, 1024, 1024, 0, 0, 0);
  // 9) XC += lif(SRR*(H*Wcv^T))   (4-phase, K=4096)
  gemm4p<5><<<dim3(8, 32), blk512, 0, stream>>>(
      H16, bWcv, XC, 4096, 1024, 4096, 4096, nullptr, nullptr, nullptr, SRR);
  // 10) tail
  cvt_rtok<<<1024, blk, 0, stream>>>(XC, rtok);
  gemm_bf16<64, 64, 0, 2, 2><<<dim3(4, 4, 8), blk, 0, stream>>>(
      bWrm, rtok, Mt, 256, 256, 1024, 1024, 0, (int64_t)256 * 1024,
      (int64_t)256 * 256, nullptr, nullptr, nullptr, nullptr, 0);
  gemm_bf16<64, 64, 3, 2, 2><<<dim3(16, 4, 8), blk, 0, stream>>>(
      Mt, bWam, out, 256, 1024, 256, 256, (int64_t)256 * 256, 0,
      (int64_t)256 * 1024, brm, Sb, bam, XC, (int64_t)512 * 1024);
}